// Round 3
// baseline (1065.698 us; speedup 1.0000x reference)
//
#include <hip/hip_runtime.h>
#include <hip/hip_bf16.h>
#include <math.h>

#define B_   2
#define N_   2000
#define T_   24
#define NX_  8
#define H_   64
#define G_   (B_*T_)        // 48 graphs
#define E_   32000
#define BN_  (B_*N_)        // 4000 sequences
#define TH_  (T_*H_)        // 1536
#define NTH_ (N_*T_*H_)     // 3072000
#define GNH_ (G_*N_*H_)     // 6144000
#define NPARAM_ 811340      // total canonical fp32 param elements
#define NPARAM_PAD_ 811392

using bf16 = __hip_bfloat16;

__device__ __forceinline__ float uasf(unsigned u){ return __uint_as_float(u); }
__device__ __forceinline__ float wave_sum(float v){
  #pragma unroll
  for (int o = 32; o > 0; o >>= 1) v += __shfl_xor(v, o, 64);
  return v;
}
__device__ __forceinline__ float wave_max(float v){
  #pragma unroll
  for (int o = 32; o > 0; o >>= 1) v = fmaxf(v, __shfl_xor(v, o, 64));
  return v;
}
__device__ __forceinline__ float sigf(float x){ return 1.f/(1.f + __expf(-x)); }
__device__ __forceinline__ float tanhfast(float x){ return 2.f/(1.f + __expf(-2.f*x)) - 1.f; }
__device__ __forceinline__ float gelu_exact(float x){ return 0.5f*x*(1.f + erff(x*0.70710678118654752f)); }
__device__ __forceinline__ unsigned f2bf_rtn(float f){
  unsigned u = __float_as_uint(f);
  u += 0x7fffu + ((u >> 16) & 1u);
  return u >> 16;
}

// ---------- dtype detection: are float inputs bf16-packed or fp32? ----------
// Looks at low 16 bits of x's 32-bit words. bf16-packed: lo half is a real
// bf16 from N(0,1) -> exponent byte in [100,140] ~always. fp32: lo half is
// random mantissa bits -> ~16% hit that range.
__global__ void detect_kernel(const unsigned* __restrict__ xw, int* __restrict__ flag){
  __shared__ int cnt;
  if (threadIdx.x == 0) cnt = 0;
  __syncthreads();
  int c = 0;
  for (int i = threadIdx.x; i < 4096; i += 256){
    unsigned e = (xw[i] >> 7) & 0xffu;   // bf16 exponent of lo half
    if (e >= 100u && e <= 140u) c++;
  }
  atomicAdd(&cnt, c);
  __syncthreads();
  if (threadIdx.x == 0) *flag = (cnt > 3276) ? 1 : 0;  // 1 = bf16 inputs
}

// ---------- canonicalize all float params to fp32 block ----------
struct ConvArgs {
  const void* src[19];
  int off[20];          // cumulative offsets into canonical block
};
__global__ __launch_bounds__(256) void convert_kernel(
    ConvArgs a, const int* __restrict__ flag, float* __restrict__ dst){
  int i = blockIdx.x*256 + threadIdx.x;
  if (i >= NPARAM_) return;
  int seg = 0;
  while (i >= a.off[seg+1]) seg++;
  int j = i - a.off[seg];
  float v;
  if (*flag){
    v = uasf(((unsigned)((const unsigned short*)a.src[seg])[j]) << 16);
  } else {
    v = ((const float*)a.src[seg])[j];
  }
  dst[i] = v;
}

// ---------- fc: x[B,N,T,8] @ W[8,64] + b -> bufA in graph layout [B,T,N,64] ----------
__global__ __launch_bounds__(256) void fc_kernel(
    const float* __restrict__ x, const float* __restrict__ W,
    const float* __restrict__ b, float* __restrict__ xh){
  int tid = blockIdx.x*256 + threadIdx.x;           // 6,144,000 threads
  int h   = tid & 63;
  int bnt = tid >> 6;
  int t = bnt % T_;
  int n = (bnt / T_) % N_;
  int bb = bnt / (T_*N_);
  const float* xr = x + ((size_t)(bb*N_ + n)*T_ + t)*NX_;
  float s = b[h];
  #pragma unroll
  for (int k = 0; k < NX_; ++k) s = fmaf(xr[k], W[k*H_ + h], s);
  xh[((size_t)(bb*T_ + t)*N_ + n)*H_ + h] = s;
}

// ---------- CSR build ----------
__global__ void zero_kernel(int* p, int n){
  int i = blockIdx.x*256 + threadIdx.x;
  if (i < n) p[i] = 0;
}
__global__ void count_kernel(const int* __restrict__ dst, int* __restrict__ counts){
  int e = blockIdx.x*256 + threadIdx.x;
  if (e < E_) atomicAdd(&counts[dst[e]], 1);
}
__global__ void scan_kernel(const int* __restrict__ counts, int* __restrict__ offs){
  int lane = threadIdx.x & 63;
  int base = 0;
  for (int c0 = 0; c0 < N_; c0 += 64){
    int i = c0 + lane;
    int v = (i < N_) ? counts[i] : 0;
    int xv = v;
    #pragma unroll
    for (int o = 1; o < 64; o <<= 1){
      int y = __shfl_up(xv, o, 64);
      if (lane >= o) xv += y;
    }
    if (i < N_) offs[i] = base + xv - v;   // exclusive
    base += __shfl(xv, 63, 64);
  }
  if (lane == 0) offs[N_] = base;          // == E_
}
__global__ void fill_kernel(const int* __restrict__ src, const int* __restrict__ dst,
                            const int* __restrict__ offs, int* __restrict__ cursor,
                            int* __restrict__ csrc){
  int e = blockIdx.x*256 + threadIdx.x;
  if (e >= E_) return;
  int d = dst[e];
  int pos = atomicAdd(&cursor[d], 1);
  csrc[offs[d] + pos] = src[e];
}

// ---------- GAT h = xin @ W; es = h.asrc; ed = h.adst ----------
// SCR=0: xin read as [G*N, 64] flat. SCR=1: scrambled read (raw-reshape semantics).
template<int SCR>
__global__ __launch_bounds__(256) void gat_h_kernel(
    const float* __restrict__ xin, const float* __restrict__ W,
    const float* __restrict__ asrc, const float* __restrict__ adst,
    float* __restrict__ hbuf, float* __restrict__ es, float* __restrict__ ed){
  int lane = threadIdx.x & 63, wave = threadIdx.x >> 6;
  float Wc[64];                               // W[k][lane]
  #pragma unroll
  for (int k = 0; k < 64; ++k) Wc[k] = W[k*H_ + lane];
  float av = asrc[lane], dv = adst[lane];
  int gw = blockIdx.x*4 + wave;               // 1600 waves total
  const int PAIRS = 60;                       // 1600*60 = 96000 (g,n) pairs
  int p0 = gw * PAIRS;
  for (int p = p0; p < p0 + PAIRS; ++p){
    float xk;
    if (SCR){
      int g = p / N_, n = p - g*N_;
      int bb = g / T_, t = g - bb*T_;
      xk = xin[(size_t)bb*NTH_ + (size_t)n*TH_ + (size_t)t*H_ + lane];
    } else {
      xk = xin[(size_t)p*H_ + lane];
    }
    float hj = 0.f;
    #pragma unroll
    for (int k = 0; k < 64; ++k) hj = fmaf(__shfl(xk, k, 64), Wc[k], hj);
    hbuf[(size_t)p*H_ + lane] = hj;
    float e1 = wave_sum(hj * av);
    float e2 = wave_sum(hj * dv);
    if (lane == 0){ es[p] = e1; ed[p] = e2; }
  }
}

// ---------- GAT aggregate: segment softmax + weighted sum + bias + gelu ----------
__global__ __launch_bounds__(256) void gat_agg_kernel(
    const float* __restrict__ hbuf, const float* __restrict__ es, const float* __restrict__ ed,
    const int* __restrict__ offs, const int* __restrict__ csrc,
    const float* __restrict__ bias, float* __restrict__ gout){
  int lane = threadIdx.x & 63, wave = threadIdx.x >> 6;
  int gd = blockIdx.x*4 + wave;               // 96000 (g,d) pairs
  int g = gd / N_, d = gd - g*N_;
  int start = offs[d], deg = offs[d+1] - start;
  const float* esg = es + (size_t)g*N_;
  float edv = ed[(size_t)g*N_ + d];

  float m = -1e30f;
  for (int i = lane; i < deg; i += 64){
    int s = csrc[start + i];
    float sc = esg[s] + edv; sc = sc > 0.f ? sc : 0.2f*sc;
    m = fmaxf(m, sc);
  }
  m = wave_max(m);
  float ssum = 0.f;
  for (int i = lane; i < deg; i += 64){
    int s = csrc[start + i];
    float sc = esg[s] + edv; sc = sc > 0.f ? sc : 0.2f*sc;
    ssum += __expf(sc - m);
  }
  ssum = wave_sum(ssum);
  float inv = 1.f/(ssum + 1e-16f);

  float acc = 0.f;
  for (int i = 0; i < deg; ++i){
    int s = csrc[start + i];
    float sc = esg[s] + edv; sc = sc > 0.f ? sc : 0.2f*sc;
    float alpha = __expf(sc - m) * inv;
    acc = fmaf(alpha, hbuf[((size_t)g*N_ + s)*H_ + lane], acc);
  }
  float val = gelu_exact(acc + bias[lane]);
  gout[(size_t)gd*H_ + lane] = val;           // natural [B,T,N,H] physical
}

// ---------- fused LSTM: xz GEMM + recurrence; 2 sequences per wave ----------
__global__ __launch_bounds__(256) void lstm_fused_kernel(
    const float* __restrict__ xin,            // g2out physical flat == [BN*T, 64]
    const float* __restrict__ Wih, const float* __restrict__ Whh,
    const float* __restrict__ bih, const float* __restrict__ bhh,
    float* __restrict__ hfin){
  __shared__ uint2 Wh[4096];   // [k][l] -> (pack(i,f), pack(g,o)) bf16-RTN of W[gate*64+l, k]
  __shared__ uint2 Wi[4096];
  int tid = threadIdx.x;
  for (int idx = tid; idx < 4096; idx += 256){
    int l = idx & 63, k = idx >> 6;
    unsigned a0 = f2bf_rtn(Whh[(0*64 + l)*64 + k]);
    unsigned a1 = f2bf_rtn(Whh[(1*64 + l)*64 + k]);
    unsigned a2 = f2bf_rtn(Whh[(2*64 + l)*64 + k]);
    unsigned a3 = f2bf_rtn(Whh[(3*64 + l)*64 + k]);
    Wh[idx] = make_uint2(a0 | (a1 << 16), a2 | (a3 << 16));
    unsigned b0 = f2bf_rtn(Wih[(0*64 + l)*64 + k]);
    unsigned b1 = f2bf_rtn(Wih[(1*64 + l)*64 + k]);
    unsigned b2 = f2bf_rtn(Wih[(2*64 + l)*64 + k]);
    unsigned b3 = f2bf_rtn(Wih[(3*64 + l)*64 + k]);
    Wi[idx] = make_uint2(b0 | (b1 << 16), b2 | (b3 << 16));
  }
  __syncthreads();
  int lane = tid & 63, wave = tid >> 6;
  int s0 = (blockIdx.x*4 + wave)*2;           // 500 blocks -> 4000 sequences
  float bg0 = bih[0*64+lane] + bhh[0*64+lane];
  float bg1 = bih[1*64+lane] + bhh[1*64+lane];
  float bg2 = bih[2*64+lane] + bhh[2*64+lane];
  float bg3 = bih[3*64+lane] + bhh[3*64+lane];
  float h0=0.f,c0=0.f,h1=0.f,c1=0.f;
  for (int t = 0; t < T_; ++t){
    float x0 = xin[((size_t)(s0*T_ + t))*64 + lane];
    float x1 = xin[((size_t)((s0+1)*T_ + t))*64 + lane];
    float z00=bg0, z01=bg1, z02=bg2, z03=bg3;
    float z10=bg0, z11=bg1, z12=bg2, z13=bg3;
    #pragma unroll
    for (int k = 0; k < 64; ++k){
      uint2 uh = Wh[k*64 + lane];
      uint2 ui = Wi[k*64 + lane];
      float wi = uasf(uh.x << 16), wf = uasf(uh.x & 0xffff0000u);
      float wg = uasf(uh.y << 16), wo = uasf(uh.y & 0xffff0000u);
      float vi = uasf(ui.x << 16), vf = uasf(ui.x & 0xffff0000u);
      float vg = uasf(ui.y << 16), vo = uasf(ui.y & 0xffff0000u);
      float a0 = __shfl(h0, k, 64), a1 = __shfl(h1, k, 64);
      float e0 = __shfl(x0, k, 64), e1 = __shfl(x1, k, 64);
      z00 = fmaf(a0, wi, fmaf(e0, vi, z00));
      z01 = fmaf(a0, wf, fmaf(e0, vf, z01));
      z02 = fmaf(a0, wg, fmaf(e0, vg, z02));
      z03 = fmaf(a0, wo, fmaf(e0, vo, z03));
      z10 = fmaf(a1, wi, fmaf(e1, vi, z10));
      z11 = fmaf(a1, wf, fmaf(e1, vf, z11));
      z12 = fmaf(a1, wg, fmaf(e1, vg, z12));
      z13 = fmaf(a1, wo, fmaf(e1, vo, z13));
    }
    c0 = sigf(z01)*c0 + sigf(z00)*tanhfast(z02); h0 = sigf(z03)*tanhfast(c0);
    c1 = sigf(z11)*c1 + sigf(z10)*tanhfast(z12); h1 = sigf(z13)*tanhfast(c1);
  }
  hfin[(size_t)s0*64 + lane]     = h0;
  hfin[(size_t)(s0+1)*64 + lane] = h1;
}

// ---------- LayerNorm (last step) + dense [64,12]; dual-dtype store ----------
__global__ __launch_bounds__(256) void final_kernel(
    const float* __restrict__ hfin, const float* __restrict__ lng, const float* __restrict__ lnb,
    const float* __restrict__ dW, const float* __restrict__ db,
    const int* __restrict__ flag, void* __restrict__ outv){
  __shared__ float sm[4][64];
  int lane = threadIdx.x & 63, wave = threadIdx.x >> 6;
  int s = blockIdx.x*4 + wave;                // 1000 blocks -> 4000 nodes
  float h = hfin[(size_t)s*64 + lane];
  float mu = wave_sum(h) * (1.f/64.f);
  float dev = h - mu;
  float var = wave_sum(dev*dev) * (1.f/64.f);
  float hn = dev * rsqrtf(var + 1e-5f) * lng[lane] + lnb[lane];
  sm[wave][lane] = hn;
  __syncthreads();
  if (lane < 12){
    float o = db[lane];
    #pragma unroll
    for (int k = 0; k < 64; ++k) o = fmaf(sm[wave][k], dW[k*12 + lane], o);
    if (*flag) ((unsigned short*)outv)[(size_t)s*12 + lane] = (unsigned short)f2bf_rtn(o);
    else       ((float*)outv)[(size_t)s*12 + lane] = o;
  }
}

extern "C" void kernel_launch(void* const* d_in, const int* in_sizes, int n_in,
                              void* d_out, int out_size, void* d_ws, size_t ws_size,
                              hipStream_t stream) {
  const int* esrc = (const int*)d_in[1];
  const int* edst = (const int*)d_in[2];

  // canonical fp32 param block offsets
  static const int sizes[19] = {768000, 512, 64, 4096, 64, 64, 64, 4096, 64, 64, 64,
                                16384, 16384, 256, 256, 64, 64, 768, 12};
  static const int srcidx[19] = {0, 3, 4, 5, 6, 7, 8, 9, 10, 11, 12,
                                 13, 14, 15, 16, 17, 18, 19, 20};
  ConvArgs ca;
  {
    int acc = 0;
    for (int i = 0; i < 19; ++i){ ca.src[i] = d_in[srcidx[i]]; ca.off[i] = acc; acc += sizes[i]; }
    ca.off[19] = acc;   // == NPARAM_
  }

  float* P     = (float*)d_ws;               // [NPARAM_PAD_]
  float* bufA  = P + NPARAM_PAD_;            // [6,144,000] xh -> gout1 -> g2out
  float* bufB  = bufA + (size_t)GNH_;        // [6,144,000] h1 -> h2 -> hfin
  float* esb   = bufB + (size_t)GNH_;        // [96000]
  float* edb   = esb  + (size_t)G_*N_;       // [96000]
  int*   counts= (int*)(edb + (size_t)G_*N_);
  int*   cursor= counts + N_;
  int*   offs  = cursor + N_;                // [N_+1]
  int*   csrc  = offs + (N_ + 1);            // [E_]
  int*   flag  = csrc + E_;                  // [1]
  float* hfin  = bufB;                       // alias (bufB dead after agg#2)

  const float* px   = P;
  const float* pfcW = P + 768000;
  const float* pfcb = P + 768512;
  const float* pg1W = P + 768576;
  const float* pg1b = P + 772672;
  const float* pg1as= P + 772736;
  const float* pg1ad= P + 772800;
  const float* pg2W = P + 772864;
  const float* pg2b = P + 776960;
  const float* pg2as= P + 777024;
  const float* pg2ad= P + 777088;
  const float* pWih = P + 777152;
  const float* pWhh = P + 793536;
  const float* pbih = P + 809920;
  const float* pbhh = P + 810176;
  const float* plng = P + 810432;
  const float* plnb = P + 810496;
  const float* pdW  = P + 810560;
  const float* pdb  = P + 811328;

  detect_kernel<<<1, 256, 0, stream>>>((const unsigned*)d_in[0], flag);
  convert_kernel<<<(NPARAM_ + 255)/256, 256, 0, stream>>>(ca, flag, P);

  fc_kernel<<<24000, 256, 0, stream>>>(px, pfcW, pfcb, bufA);

  zero_kernel<<<16, 256, 0, stream>>>(counts, 2*N_);
  count_kernel<<<(E_+255)/256, 256, 0, stream>>>(edst, counts);
  scan_kernel<<<1, 64, 0, stream>>>(counts, offs);
  fill_kernel<<<(E_+255)/256, 256, 0, stream>>>(esrc, edst, offs, cursor, csrc);

  gat_h_kernel<0><<<400, 256, 0, stream>>>(bufA, pg1W, pg1as, pg1ad, bufB, esb, edb);
  gat_agg_kernel<<<24000, 256, 0, stream>>>(bufB, esb, edb, offs, csrc, pg1b, bufA);

  gat_h_kernel<1><<<400, 256, 0, stream>>>(bufA, pg2W, pg2as, pg2ad, bufB, esb, edb);
  gat_agg_kernel<<<24000, 256, 0, stream>>>(bufB, esb, edb, offs, csrc, pg2b, bufA);

  lstm_fused_kernel<<<500, 256, 0, stream>>>(bufA, pWih, pWhh, pbih, pbhh, hfin);
  final_kernel<<<1000, 256, 0, stream>>>(hfin, plng, plnb, pdW, pdb, flag, d_out);
}

// Round 4
// 800.107 us; speedup vs baseline: 1.3319x; 1.3319x over previous
//
#include <hip/hip_runtime.h>
#include <hip/hip_bf16.h>
#include <math.h>

#define B_   2
#define N_   2000
#define T_   24
#define NX_  8
#define H_   64
#define G_   (B_*T_)        // 48 graphs
#define E_   32000
#define BN_  (B_*N_)        // 4000 sequences
#define TH_  (T_*H_)        // 1536
#define NTH_ (N_*T_*H_)     // 3072000
#define GNH_ (G_*N_*H_)     // 6144000
#define NPARAM_ 811340      // total canonical fp32 param elements
#define NPARAM_PAD_ 811392
#define LSTM_PAD 72         // padded H-row (bf16 elems): 144B stride, 16B aligned, <=2-way banks

using bf16 = __hip_bfloat16;
typedef short bf16x8 __attribute__((ext_vector_type(8)));
typedef float f32x4  __attribute__((ext_vector_type(4)));

__device__ __forceinline__ float uasf(unsigned u){ return __uint_as_float(u); }
__device__ __forceinline__ float wave_sum(float v){
  #pragma unroll
  for (int o = 32; o > 0; o >>= 1) v += __shfl_xor(v, o, 64);
  return v;
}
__device__ __forceinline__ float wave_max(float v){
  #pragma unroll
  for (int o = 32; o > 0; o >>= 1) v = fmaxf(v, __shfl_xor(v, o, 64));
  return v;
}
__device__ __forceinline__ float fastrcp(float x){ return __builtin_amdgcn_rcpf(x); }
__device__ __forceinline__ float sigf(float x){ return fastrcp(1.f + __expf(-x)); }
__device__ __forceinline__ float tanhfast(float x){ return 1.f - 2.f*fastrcp(1.f + __expf(2.f*x)); }
__device__ __forceinline__ float gelu_exact(float x){ return 0.5f*x*(1.f + erff(x*0.70710678118654752f)); }
__device__ __forceinline__ unsigned f2bf_rtn(float f){
  unsigned u = __float_as_uint(f);
  u += 0x7fffu + ((u >> 16) & 1u);
  return u >> 16;
}
__device__ __forceinline__ bf16x8 pack8(float4 a, float4 b){
  bf16x8 v;
  v[0]=(short)f2bf_rtn(a.x); v[1]=(short)f2bf_rtn(a.y);
  v[2]=(short)f2bf_rtn(a.z); v[3]=(short)f2bf_rtn(a.w);
  v[4]=(short)f2bf_rtn(b.x); v[5]=(short)f2bf_rtn(b.y);
  v[6]=(short)f2bf_rtn(b.z); v[7]=(short)f2bf_rtn(b.w);
  return v;
}

// ---------- dtype detection: are float inputs bf16-packed or fp32? ----------
__global__ void detect_kernel(const unsigned* __restrict__ xw, int* __restrict__ flag){
  __shared__ int cnt;
  if (threadIdx.x == 0) cnt = 0;
  __syncthreads();
  int c = 0;
  for (int i = threadIdx.x; i < 4096; i += 256){
    unsigned e = (xw[i] >> 7) & 0xffu;   // bf16 exponent of lo half
    if (e >= 100u && e <= 140u) c++;
  }
  atomicAdd(&cnt, c);
  __syncthreads();
  if (threadIdx.x == 0) *flag = (cnt > 3276) ? 1 : 0;  // 1 = bf16 inputs
}

// ---------- canonicalize all float params to fp32 block ----------
struct ConvArgs {
  const void* src[19];
  int off[20];
};
__global__ __launch_bounds__(256) void convert_kernel(
    ConvArgs a, const int* __restrict__ flag, float* __restrict__ dst){
  int i = blockIdx.x*256 + threadIdx.x;
  if (i >= NPARAM_) return;
  int seg = 0;
  while (i >= a.off[seg+1]) seg++;
  int j = i - a.off[seg];
  float v;
  if (*flag){
    v = uasf(((unsigned)((const unsigned short*)a.src[seg])[j]) << 16);
  } else {
    v = ((const float*)a.src[seg])[j];
  }
  dst[i] = v;
}

// ---------- fc: x[B,N,T,8] @ W[8,64] + b -> bufA in graph layout [B,T,N,64] ----------
__global__ __launch_bounds__(256) void fc_kernel(
    const float* __restrict__ x, const float* __restrict__ W,
    const float* __restrict__ b, float* __restrict__ xh){
  int tid = blockIdx.x*256 + threadIdx.x;
  int h   = tid & 63;
  int bnt = tid >> 6;
  int t = bnt % T_;
  int n = (bnt / T_) % N_;
  int bb = bnt / (T_*N_);
  const float* xr = x + ((size_t)(bb*N_ + n)*T_ + t)*NX_;
  float s = b[h];
  #pragma unroll
  for (int k = 0; k < NX_; ++k) s = fmaf(xr[k], W[k*H_ + h], s);
  xh[((size_t)(bb*T_ + t)*N_ + n)*H_ + h] = s;
}

// ---------- CSR build ----------
__global__ void zero_kernel(int* p, int n){
  int i = blockIdx.x*256 + threadIdx.x;
  if (i < n) p[i] = 0;
}
__global__ void count_kernel(const int* __restrict__ dst, int* __restrict__ counts){
  int e = blockIdx.x*256 + threadIdx.x;
  if (e < E_) atomicAdd(&counts[dst[e]], 1);
}
__global__ void scan_kernel(const int* __restrict__ counts, int* __restrict__ offs){
  int lane = threadIdx.x & 63;
  int base = 0;
  for (int c0 = 0; c0 < N_; c0 += 64){
    int i = c0 + lane;
    int v = (i < N_) ? counts[i] : 0;
    int xv = v;
    #pragma unroll
    for (int o = 1; o < 64; o <<= 1){
      int y = __shfl_up(xv, o, 64);
      if (lane >= o) xv += y;
    }
    if (i < N_) offs[i] = base + xv - v;
    base += __shfl(xv, 63, 64);
  }
  if (lane == 0) offs[N_] = base;
}
__global__ void fill_kernel(const int* __restrict__ src, const int* __restrict__ dst,
                            const int* __restrict__ offs, int* __restrict__ cursor,
                            int* __restrict__ csrc){
  int e = blockIdx.x*256 + threadIdx.x;
  if (e >= E_) return;
  int d = dst[e];
  int pos = atomicAdd(&cursor[d], 1);
  csrc[offs[d] + pos] = src[e];
}

// ---------- GAT h = xin @ W; es = h.asrc; ed = h.adst ----------
template<int SCR>
__global__ __launch_bounds__(256) void gat_h_kernel(
    const float* __restrict__ xin, const float* __restrict__ W,
    const float* __restrict__ asrc, const float* __restrict__ adst,
    float* __restrict__ hbuf, float* __restrict__ es, float* __restrict__ ed){
  int lane = threadIdx.x & 63, wave = threadIdx.x >> 6;
  float Wc[64];
  #pragma unroll
  for (int k = 0; k < 64; ++k) Wc[k] = W[k*H_ + lane];
  float av = asrc[lane], dv = adst[lane];
  int gw = blockIdx.x*4 + wave;
  const int PAIRS = 60;
  int p0 = gw * PAIRS;
  for (int p = p0; p < p0 + PAIRS; ++p){
    float xk;
    if (SCR){
      int g = p / N_, n = p - g*N_;
      int bb = g / T_, t = g - bb*T_;
      xk = xin[(size_t)bb*NTH_ + (size_t)n*TH_ + (size_t)t*H_ + lane];
    } else {
      xk = xin[(size_t)p*H_ + lane];
    }
    float hj = 0.f;
    #pragma unroll
    for (int k = 0; k < 64; ++k) hj = fmaf(__shfl(xk, k, 64), Wc[k], hj);
    hbuf[(size_t)p*H_ + lane] = hj;
    float e1 = wave_sum(hj * av);
    float e2 = wave_sum(hj * dv);
    if (lane == 0){ es[p] = e1; ed[p] = e2; }
  }
}

// ---------- GAT aggregate: segment softmax + weighted sum + bias + gelu ----------
__global__ __launch_bounds__(256) void gat_agg_kernel(
    const float* __restrict__ hbuf, const float* __restrict__ es, const float* __restrict__ ed,
    const int* __restrict__ offs, const int* __restrict__ csrc,
    const float* __restrict__ bias, float* __restrict__ gout){
  int lane = threadIdx.x & 63, wave = threadIdx.x >> 6;
  int gd = blockIdx.x*4 + wave;
  int g = gd / N_, d = gd - g*N_;
  int start = offs[d], deg = offs[d+1] - start;
  const float* esg = es + (size_t)g*N_;
  float edv = ed[(size_t)g*N_ + d];

  float m = -1e30f;
  for (int i = lane; i < deg; i += 64){
    int s = csrc[start + i];
    float sc = esg[s] + edv; sc = sc > 0.f ? sc : 0.2f*sc;
    m = fmaxf(m, sc);
  }
  m = wave_max(m);
  float ssum = 0.f;
  for (int i = lane; i < deg; i += 64){
    int s = csrc[start + i];
    float sc = esg[s] + edv; sc = sc > 0.f ? sc : 0.2f*sc;
    ssum += __expf(sc - m);
  }
  ssum = wave_sum(ssum);
  float inv = fastrcp(ssum + 1e-16f);

  float acc = 0.f;
  for (int i = 0; i < deg; ++i){
    int s = csrc[start + i];
    float sc = esg[s] + edv; sc = sc > 0.f ? sc : 0.2f*sc;
    float alpha = __expf(sc - m) * inv;
    acc = fmaf(alpha, hbuf[((size_t)g*N_ + s)*H_ + lane], acc);
  }
  float val = gelu_exact(acc + bias[lane]);
  gout[(size_t)gd*H_ + lane] = val;
}

// ---------- LSTM via MFMA: Z = [H | X_t] @ [Whh^T ; Wih^T], K=128 fused ----------
// 250 blocks x 16 seqs. Wave w owns gate-channel group j in [16w,16w+16).
// A layout (16x16x32): m=lane&15, k=quad*8+j   [HW-verified]
// C/D layout:          col=lane&15, row=quad*4+reg [HW-verified]
// B layout: n=lane&15, k=quad*8+j (transpose-dual of A)
__global__ __launch_bounds__(256) void lstm_mfma_kernel(
    const float* __restrict__ xin,   // flat [BN*T, 64]: row = seq*T + t
    const float* __restrict__ Wih,   // [256][64] row-major
    const float* __restrict__ Whh,   // [256][64] row-major
    const float* __restrict__ bih, const float* __restrict__ bhh,
    float* __restrict__ hfin){
  __shared__ __align__(16) unsigned short Hlds[16*LSTM_PAD];
  int tid = threadIdx.x;
  int lane = tid & 63, wave = tid >> 6;
  int q = lane >> 4, c = lane & 15;
  int s0 = blockIdx.x * 16;

  // Preload B-frags: gate g, k-step ks (ks 0,1 = Whh k=0..63; ks 2,3 = Wih)
  bf16x8 Bf[4][4];
  #pragma unroll
  for (int g = 0; g < 4; ++g){
    int n = g*64 + wave*16 + c;
    #pragma unroll
    for (int ks = 0; ks < 4; ++ks){
      const float* srcp = (ks < 2) ? (Whh + (size_t)n*64 + ks*32 + q*8)
                                   : (Wih + (size_t)n*64 + (ks-2)*32 + q*8);
      float4 a = ((const float4*)srcp)[0];
      float4 b = ((const float4*)srcp)[1];
      Bf[g][ks] = pack8(a, b);
    }
  }
  float bsum[4];
  #pragma unroll
  for (int g = 0; g < 4; ++g){
    int n = g*64 + wave*16 + c;
    bsum[g] = bih[n] + bhh[n];
  }
  for (int i = tid; i < 16*LSTM_PAD; i += 256) Hlds[i] = 0;
  float cst[4] = {0.f, 0.f, 0.f, 0.f};
  __syncthreads();

  for (int t = 0; t < T_; ++t){
    // A_x: seq s0+c, x-part k = quad*8+j (+32 for ks=3)
    const float4* xr4 = (const float4*)(xin + ((size_t)(s0 + c)*T_ + t)*64);
    float4 x0 = xr4[q*2],     x1 = xr4[q*2 + 1];
    float4 x2 = xr4[8 + q*2], x3 = xr4[8 + q*2 + 1];
    bf16x8 Ax0 = pack8(x0, x1);
    bf16x8 Ax1 = pack8(x2, x3);
    // A_h from LDS: row c, 16B chunks (aligned: 144B row stride)
    const bf16x8* hrow = (const bf16x8*)(Hlds + c*LSTM_PAD);
    bf16x8 Ah0 = hrow[q];
    bf16x8 Ah1 = hrow[4 + q];

    f32x4 acc[4];
    #pragma unroll
    for (int g = 0; g < 4; ++g){ acc[g][0]=bsum[g]; acc[g][1]=bsum[g]; acc[g][2]=bsum[g]; acc[g][3]=bsum[g]; }
    #pragma unroll
    for (int g = 0; g < 4; ++g) acc[g] = __builtin_amdgcn_mfma_f32_16x16x32_bf16(Ah0, Bf[g][0], acc[g], 0, 0, 0);
    #pragma unroll
    for (int g = 0; g < 4; ++g) acc[g] = __builtin_amdgcn_mfma_f32_16x16x32_bf16(Ah1, Bf[g][1], acc[g], 0, 0, 0);
    #pragma unroll
    for (int g = 0; g < 4; ++g) acc[g] = __builtin_amdgcn_mfma_f32_16x16x32_bf16(Ax0, Bf[g][2], acc[g], 0, 0, 0);
    #pragma unroll
    for (int g = 0; g < 4; ++g) acc[g] = __builtin_amdgcn_mfma_f32_16x16x32_bf16(Ax1, Bf[g][3], acc[g], 0, 0, 0);

    float hv[4];
    #pragma unroll
    for (int r = 0; r < 4; ++r){
      float zi = acc[0][r], zf = acc[1][r], zg = acc[2][r], zo = acc[3][r];
      cst[r] = sigf(zf)*cst[r] + sigf(zi)*tanhfast(zg);
      hv[r] = sigf(zo)*tanhfast(cst[r]);
    }
    if (t == T_-1){
      #pragma unroll
      for (int r = 0; r < 4; ++r)
        hfin[(size_t)(s0 + q*4 + r)*64 + wave*16 + c] = hv[r];
    } else {
      __syncthreads();   // all waves' A-reads done (register-resident) before overwrite
      #pragma unroll
      for (int r = 0; r < 4; ++r)
        Hlds[(q*4 + r)*LSTM_PAD + wave*16 + c] = (unsigned short)f2bf_rtn(hv[r]);
      __syncthreads();   // writes visible before next iteration's reads
    }
  }
}

// ---------- LayerNorm (last step) + dense [64,12]; dual-dtype store ----------
__global__ __launch_bounds__(256) void final_kernel(
    const float* __restrict__ hfin, const float* __restrict__ lng, const float* __restrict__ lnb,
    const float* __restrict__ dW, const float* __restrict__ db,
    const int* __restrict__ flag, void* __restrict__ outv){
  __shared__ float sm[4][64];
  int lane = threadIdx.x & 63, wave = threadIdx.x >> 6;
  int s = blockIdx.x*4 + wave;
  float h = hfin[(size_t)s*64 + lane];
  float mu = wave_sum(h) * (1.f/64.f);
  float dev = h - mu;
  float var = wave_sum(dev*dev) * (1.f/64.f);
  float hn = dev * rsqrtf(var + 1e-5f) * lng[lane] + lnb[lane];
  sm[wave][lane] = hn;
  __syncthreads();
  if (lane < 12){
    float o = db[lane];
    #pragma unroll
    for (int k = 0; k < 64; ++k) o = fmaf(sm[wave][k], dW[k*12 + lane], o);
    if (*flag) ((unsigned short*)outv)[(size_t)s*12 + lane] = (unsigned short)f2bf_rtn(o);
    else       ((float*)outv)[(size_t)s*12 + lane] = o;
  }
}

extern "C" void kernel_launch(void* const* d_in, const int* in_sizes, int n_in,
                              void* d_out, int out_size, void* d_ws, size_t ws_size,
                              hipStream_t stream) {
  const int* esrc = (const int*)d_in[1];
  const int* edst = (const int*)d_in[2];

  static const int sizes[19] = {768000, 512, 64, 4096, 64, 64, 64, 4096, 64, 64, 64,
                                16384, 16384, 256, 256, 64, 64, 768, 12};
  static const int srcidx[19] = {0, 3, 4, 5, 6, 7, 8, 9, 10, 11, 12,
                                 13, 14, 15, 16, 17, 18, 19, 20};
  ConvArgs ca;
  {
    int acc = 0;
    for (int i = 0; i < 19; ++i){ ca.src[i] = d_in[srcidx[i]]; ca.off[i] = acc; acc += sizes[i]; }
    ca.off[19] = acc;
  }

  float* P     = (float*)d_ws;               // [NPARAM_PAD_]
  float* bufA  = P + NPARAM_PAD_;            // xh -> gout1 -> g2out
  float* bufB  = bufA + (size_t)GNH_;        // h1 -> h2 -> hfin
  float* esb   = bufB + (size_t)GNH_;
  float* edb   = esb  + (size_t)G_*N_;
  int*   counts= (int*)(edb + (size_t)G_*N_);
  int*   cursor= counts + N_;
  int*   offs  = cursor + N_;
  int*   csrc  = offs + (N_ + 1);
  int*   flag  = csrc + E_;
  float* hfin  = bufB;

  const float* px   = P;
  const float* pfcW = P + 768000;
  const float* pfcb = P + 768512;
  const float* pg1W = P + 768576;
  const float* pg1b = P + 772672;
  const float* pg1as= P + 772736;
  const float* pg1ad= P + 772800;
  const float* pg2W = P + 772864;
  const float* pg2b = P + 776960;
  const float* pg2as= P + 777024;
  const float* pg2ad= P + 777088;
  const float* pWih = P + 777152;
  const float* pWhh = P + 793536;
  const float* pbih = P + 809920;
  const float* pbhh = P + 810176;
  const float* plng = P + 810432;
  const float* plnb = P + 810496;
  const float* pdW  = P + 810560;
  const float* pdb  = P + 811328;

  detect_kernel<<<1, 256, 0, stream>>>((const unsigned*)d_in[0], flag);
  convert_kernel<<<(NPARAM_ + 255)/256, 256, 0, stream>>>(ca, flag, P);

  fc_kernel<<<24000, 256, 0, stream>>>(px, pfcW, pfcb, bufA);

  zero_kernel<<<16, 256, 0, stream>>>(counts, 2*N_);
  count_kernel<<<(E_+255)/256, 256, 0, stream>>>(edst, counts);
  scan_kernel<<<1, 64, 0, stream>>>(counts, offs);
  fill_kernel<<<(E_+255)/256, 256, 0, stream>>>(esrc, edst, offs, cursor, csrc);

  gat_h_kernel<0><<<400, 256, 0, stream>>>(bufA, pg1W, pg1as, pg1ad, bufB, esb, edb);
  gat_agg_kernel<<<24000, 256, 0, stream>>>(bufB, esb, edb, offs, csrc, pg1b, bufA);

  gat_h_kernel<1><<<400, 256, 0, stream>>>(bufA, pg2W, pg2as, pg2ad, bufB, esb, edb);
  gat_agg_kernel<<<24000, 256, 0, stream>>>(bufB, esb, edb, offs, csrc, pg2b, bufA);

  lstm_mfma_kernel<<<250, 256, 0, stream>>>(bufA, pWih, pWhh, pbih, pbhh, hfin);
  final_kernel<<<1000, 256, 0, stream>>>(hfin, plng, plnb, pdW, pdb, flag, d_out);
}

// Round 5
// 513.704 us; speedup vs baseline: 2.0745x; 1.5575x over previous
//
#include <hip/hip_runtime.h>
#include <hip/hip_bf16.h>
#include <math.h>

#define B_   2
#define N_   2000
#define T_   24
#define NX_  8
#define H_   64
#define G_   (B_*T_)        // 48 graphs
#define E_   32000
#define BN_  (B_*N_)        // 4000 sequences
#define TH_  (T_*H_)        // 1536
#define NTH_ (N_*T_*H_)     // 3072000
#define GNH_ (G_*N_*H_)     // 6144000
#define NPARAM_ 811340      // total canonical fp32 param elements
#define NPARAM_PAD_ 811392
#define LSTM_PAD 72         // padded H-row (bf16 elems): 144B stride, 16B aligned, <=2-way banks

using bf16 = __hip_bfloat16;
typedef short bf16x8 __attribute__((ext_vector_type(8)));
typedef float f32x4  __attribute__((ext_vector_type(4)));

__device__ __forceinline__ float uasf(unsigned u){ return __uint_as_float(u); }
__device__ __forceinline__ float wave_sum(float v){
  #pragma unroll
  for (int o = 32; o > 0; o >>= 1) v += __shfl_xor(v, o, 64);
  return v;
}
__device__ __forceinline__ float wave_max(float v){
  #pragma unroll
  for (int o = 32; o > 0; o >>= 1) v = fmaxf(v, __shfl_xor(v, o, 64));
  return v;
}
__device__ __forceinline__ float fastrcp(float x){ return __builtin_amdgcn_rcpf(x); }
__device__ __forceinline__ float sigf(float x){ return fastrcp(1.f + __expf(-x)); }
__device__ __forceinline__ float tanhfast(float x){ return 1.f - 2.f*fastrcp(1.f + __expf(2.f*x)); }
__device__ __forceinline__ float gelu_exact(float x){ return 0.5f*x*(1.f + erff(x*0.70710678118654752f)); }
__device__ __forceinline__ unsigned f2bf_rtn(float f){
  unsigned u = __float_as_uint(f);
  u += 0x7fffu + ((u >> 16) & 1u);
  return u >> 16;
}
__device__ __forceinline__ bf16x8 pack8(float4 a, float4 b){
  bf16x8 v;
  v[0]=(short)f2bf_rtn(a.x); v[1]=(short)f2bf_rtn(a.y);
  v[2]=(short)f2bf_rtn(a.z); v[3]=(short)f2bf_rtn(a.w);
  v[4]=(short)f2bf_rtn(b.x); v[5]=(short)f2bf_rtn(b.y);
  v[6]=(short)f2bf_rtn(b.z); v[7]=(short)f2bf_rtn(b.w);
  return v;
}

// ---------- dtype detection: are float inputs bf16-packed or fp32? ----------
__global__ void detect_kernel(const unsigned* __restrict__ xw, int* __restrict__ flag){
  __shared__ int cnt;
  if (threadIdx.x == 0) cnt = 0;
  __syncthreads();
  int c = 0;
  for (int i = threadIdx.x; i < 4096; i += 256){
    unsigned e = (xw[i] >> 7) & 0xffu;   // bf16 exponent of lo half
    if (e >= 100u && e <= 140u) c++;
  }
  atomicAdd(&cnt, c);
  __syncthreads();
  if (threadIdx.x == 0) *flag = (cnt > 3276) ? 1 : 0;  // 1 = bf16 inputs
}

// ---------- canonicalize all float params to fp32 block ----------
struct ConvArgs {
  const void* src[19];
  int off[20];
};
__global__ __launch_bounds__(256) void convert_kernel(
    ConvArgs a, const int* __restrict__ flag, float* __restrict__ dst){
  int i = blockIdx.x*256 + threadIdx.x;
  if (i >= NPARAM_) return;
  int seg = 0;
  while (i >= a.off[seg+1]) seg++;
  int j = i - a.off[seg];
  float v;
  if (*flag){
    v = uasf(((unsigned)((const unsigned short*)a.src[seg])[j]) << 16);
  } else {
    v = ((const float*)a.src[seg])[j];
  }
  dst[i] = v;
}

// ---------- fc: x[B,N,T,8] @ W[8,64] + b -> bufA in graph layout [B,T,N,64] ----------
__global__ __launch_bounds__(256) void fc_kernel(
    const float* __restrict__ x, const float* __restrict__ W,
    const float* __restrict__ b, float* __restrict__ xh){
  int tid = blockIdx.x*256 + threadIdx.x;
  int h   = tid & 63;
  int bnt = tid >> 6;
  int t = bnt % T_;
  int n = (bnt / T_) % N_;
  int bb = bnt / (T_*N_);
  const float* xr = x + ((size_t)(bb*N_ + n)*T_ + t)*NX_;
  float s = b[h];
  #pragma unroll
  for (int k = 0; k < NX_; ++k) s = fmaf(xr[k], W[k*H_ + h], s);
  xh[((size_t)(bb*T_ + t)*N_ + n)*H_ + h] = s;
}

// ---------- CSR build ----------
__global__ void zero_kernel(int* p, int n){
  int i = blockIdx.x*256 + threadIdx.x;
  if (i < n) p[i] = 0;
}
__global__ void count_kernel(const int* __restrict__ dst, int* __restrict__ counts){
  int e = blockIdx.x*256 + threadIdx.x;
  if (e < E_) atomicAdd(&counts[dst[e]], 1);
}
__global__ void scan_kernel(const int* __restrict__ counts, int* __restrict__ offs){
  int lane = threadIdx.x & 63;
  int base = 0;
  for (int c0 = 0; c0 < N_; c0 += 64){
    int i = c0 + lane;
    int v = (i < N_) ? counts[i] : 0;
    int xv = v;
    #pragma unroll
    for (int o = 1; o < 64; o <<= 1){
      int y = __shfl_up(xv, o, 64);
      if (lane >= o) xv += y;
    }
    if (i < N_) offs[i] = base + xv - v;
    base += __shfl(xv, 63, 64);
  }
  if (lane == 0) offs[N_] = base;
}
__global__ void fill_kernel(const int* __restrict__ src, const int* __restrict__ dst,
                            const int* __restrict__ offs, int* __restrict__ cursor,
                            int* __restrict__ csrc){
  int e = blockIdx.x*256 + threadIdx.x;
  if (e >= E_) return;
  int d = dst[e];
  int pos = atomicAdd(&cursor[d], 1);
  csrc[offs[d] + pos] = src[e];
}

// ---------- GAT h = xin @ W via MFMA; es = h.asrc; ed = h.adst ----------
// One wave computes a 16x64 h-tile: 4 n-tiles x 2 k-steps = 8 MFMAs.
// A (16x16x32): m=lane&15, k=quad*8+j.  B: n=lane&15, k=quad*8+j.
// C/D: col=lane&15, row=quad*4+reg.  [HW-verified by passing LSTM kernel]
template<int SCR>
__global__ __launch_bounds__(256) void gat_h_mfma_kernel(
    const float* __restrict__ xin, const float* __restrict__ W,
    const float* __restrict__ asrc, const float* __restrict__ adst,
    float* __restrict__ hbuf, float* __restrict__ es, float* __restrict__ ed){
  int lane = threadIdx.x & 63, wave = threadIdx.x >> 6;
  int q = lane >> 4, c = lane & 15;
  // B frags from W[k][n] fp32, packed bf16-RTN
  bf16x8 Bf[4][2];
  #pragma unroll
  for (int nt = 0; nt < 4; ++nt){
    #pragma unroll
    for (int ks = 0; ks < 2; ++ks){
      bf16x8 v;
      #pragma unroll
      for (int j = 0; j < 8; ++j)
        v[j] = (short)f2bf_rtn(W[(ks*32 + q*8 + j)*H_ + nt*16 + c]);
      Bf[nt][ks] = v;
    }
  }
  float aS[4], aD[4];
  #pragma unroll
  for (int nt = 0; nt < 4; ++nt){ aS[nt] = asrc[nt*16+c]; aD[nt] = adst[nt*16+c]; }

  int w = blockIdx.x*4 + wave;            // 750 blocks * 4 = 3000 waves
  #pragma unroll
  for (int it = 0; it < 2; ++it){
    int tile = w*2 + it;                  // 0..5999
    int p0 = tile*16;
    int p  = p0 + c;                      // this lane's A row
    const float* xr;
    if (SCR){
      int g = p / N_, n = p - g*N_;
      int bb = g / T_, t = g - bb*T_;
      xr = xin + (size_t)bb*NTH_ + (size_t)n*TH_ + (size_t)t*H_;
    } else {
      xr = xin + (size_t)p*H_;
    }
    const float4* xr4 = (const float4*)xr;
    float4 x0 = xr4[q*2],     x1 = xr4[q*2 + 1];
    float4 x2 = xr4[8 + q*2], x3 = xr4[8 + q*2 + 1];
    bf16x8 A0 = pack8(x0, x1);
    bf16x8 A1 = pack8(x2, x3);

    f32x4 acc[4];
    #pragma unroll
    for (int nt = 0; nt < 4; ++nt){ acc[nt][0]=0.f; acc[nt][1]=0.f; acc[nt][2]=0.f; acc[nt][3]=0.f; }
    #pragma unroll
    for (int nt = 0; nt < 4; ++nt) acc[nt] = __builtin_amdgcn_mfma_f32_16x16x32_bf16(A0, Bf[nt][0], acc[nt], 0, 0, 0);
    #pragma unroll
    for (int nt = 0; nt < 4; ++nt) acc[nt] = __builtin_amdgcn_mfma_f32_16x16x32_bf16(A1, Bf[nt][1], acc[nt], 0, 0, 0);

    // store h tile
    #pragma unroll
    for (int nt = 0; nt < 4; ++nt){
      #pragma unroll
      for (int r = 0; r < 4; ++r)
        hbuf[(size_t)(p0 + q*4 + r)*H_ + nt*16 + c] = acc[nt][r];
    }
    // es/ed: dot h-row with asrc/adst; reduce across the 16 c-lanes per quad
    #pragma unroll
    for (int r = 0; r < 4; ++r){
      float e1 = acc[0][r]*aS[0] + acc[1][r]*aS[1] + acc[2][r]*aS[2] + acc[3][r]*aS[3];
      float e2 = acc[0][r]*aD[0] + acc[1][r]*aD[1] + acc[2][r]*aD[2] + acc[3][r]*aD[3];
      #pragma unroll
      for (int o = 8; o > 0; o >>= 1){
        e1 += __shfl_xor(e1, o, 64);
        e2 += __shfl_xor(e2, o, 64);
      }
      if (c == 0){
        es[p0 + q*4 + r] = e1;
        ed[p0 + q*4 + r] = e2;
      }
    }
  }
}

// ---------- GAT aggregate: segment softmax + weighted sum + bias + gelu ----------
__global__ __launch_bounds__(256) void gat_agg_kernel(
    const float* __restrict__ hbuf, const float* __restrict__ es, const float* __restrict__ ed,
    const int* __restrict__ offs, const int* __restrict__ csrc,
    const float* __restrict__ bias, float* __restrict__ gout){
  int lane = threadIdx.x & 63, wave = threadIdx.x >> 6;
  int gd = blockIdx.x*4 + wave;
  int g = gd / N_, d = gd - g*N_;
  int start = offs[d], deg = offs[d+1] - start;
  const float* esg = es + (size_t)g*N_;
  float edv = ed[(size_t)g*N_ + d];

  float m = -1e30f;
  for (int i = lane; i < deg; i += 64){
    int s = csrc[start + i];
    float sc = esg[s] + edv; sc = sc > 0.f ? sc : 0.2f*sc;
    m = fmaxf(m, sc);
  }
  m = wave_max(m);
  float ssum = 0.f;
  for (int i = lane; i < deg; i += 64){
    int s = csrc[start + i];
    float sc = esg[s] + edv; sc = sc > 0.f ? sc : 0.2f*sc;
    ssum += __expf(sc - m);
  }
  ssum = wave_sum(ssum);
  float inv = fastrcp(ssum + 1e-16f);

  float acc = 0.f;
  for (int i = 0; i < deg; ++i){
    int s = csrc[start + i];
    float sc = esg[s] + edv; sc = sc > 0.f ? sc : 0.2f*sc;
    float alpha = __expf(sc - m) * inv;
    acc = fmaf(alpha, hbuf[((size_t)g*N_ + s)*H_ + lane], acc);
  }
  float val = gelu_exact(acc + bias[lane]);
  gout[(size_t)gd*H_ + lane] = val;
}

// ---------- LSTM via MFMA: Z = [H | X_t] @ [Whh^T ; Wih^T], K=128 fused ----------
__global__ __launch_bounds__(256) void lstm_mfma_kernel(
    const float* __restrict__ xin,   // flat [BN*T, 64]: row = seq*T + t
    const float* __restrict__ Wih,   // [256][64] row-major
    const float* __restrict__ Whh,   // [256][64] row-major
    const float* __restrict__ bih, const float* __restrict__ bhh,
    float* __restrict__ hfin){
  __shared__ __align__(16) unsigned short Hlds[16*LSTM_PAD];
  int tid = threadIdx.x;
  int lane = tid & 63, wave = tid >> 6;
  int q = lane >> 4, c = lane & 15;
  int s0 = blockIdx.x * 16;

  bf16x8 Bf[4][4];
  #pragma unroll
  for (int g = 0; g < 4; ++g){
    int n = g*64 + wave*16 + c;
    #pragma unroll
    for (int ks = 0; ks < 4; ++ks){
      const float* srcp = (ks < 2) ? (Whh + (size_t)n*64 + ks*32 + q*8)
                                   : (Wih + (size_t)n*64 + (ks-2)*32 + q*8);
      float4 a = ((const float4*)srcp)[0];
      float4 b = ((const float4*)srcp)[1];
      Bf[g][ks] = pack8(a, b);
    }
  }
  float bsum[4];
  #pragma unroll
  for (int g = 0; g < 4; ++g){
    int n = g*64 + wave*16 + c;
    bsum[g] = bih[n] + bhh[n];
  }
  for (int i = tid; i < 16*LSTM_PAD; i += 256) Hlds[i] = 0;
  float cst[4] = {0.f, 0.f, 0.f, 0.f};
  __syncthreads();

  for (int t = 0; t < T_; ++t){
    const float4* xr4 = (const float4*)(xin + ((size_t)(s0 + c)*T_ + t)*64);
    float4 x0 = xr4[q*2],     x1 = xr4[q*2 + 1];
    float4 x2 = xr4[8 + q*2], x3 = xr4[8 + q*2 + 1];
    bf16x8 Ax0 = pack8(x0, x1);
    bf16x8 Ax1 = pack8(x2, x3);
    const bf16x8* hrow = (const bf16x8*)(Hlds + c*LSTM_PAD);
    bf16x8 Ah0 = hrow[q];
    bf16x8 Ah1 = hrow[4 + q];

    f32x4 acc[4];
    #pragma unroll
    for (int g = 0; g < 4; ++g){ acc[g][0]=bsum[g]; acc[g][1]=bsum[g]; acc[g][2]=bsum[g]; acc[g][3]=bsum[g]; }
    #pragma unroll
    for (int g = 0; g < 4; ++g) acc[g] = __builtin_amdgcn_mfma_f32_16x16x32_bf16(Ah0, Bf[g][0], acc[g], 0, 0, 0);
    #pragma unroll
    for (int g = 0; g < 4; ++g) acc[g] = __builtin_amdgcn_mfma_f32_16x16x32_bf16(Ah1, Bf[g][1], acc[g], 0, 0, 0);
    #pragma unroll
    for (int g = 0; g < 4; ++g) acc[g] = __builtin_amdgcn_mfma_f32_16x16x32_bf16(Ax0, Bf[g][2], acc[g], 0, 0, 0);
    #pragma unroll
    for (int g = 0; g < 4; ++g) acc[g] = __builtin_amdgcn_mfma_f32_16x16x32_bf16(Ax1, Bf[g][3], acc[g], 0, 0, 0);

    float hv[4];
    #pragma unroll
    for (int r = 0; r < 4; ++r){
      float zi = acc[0][r], zf = acc[1][r], zg = acc[2][r], zo = acc[3][r];
      cst[r] = sigf(zf)*cst[r] + sigf(zi)*tanhfast(zg);
      hv[r] = sigf(zo)*tanhfast(cst[r]);
    }
    if (t == T_-1){
      #pragma unroll
      for (int r = 0; r < 4; ++r)
        hfin[(size_t)(s0 + q*4 + r)*64 + wave*16 + c] = hv[r];
    } else {
      __syncthreads();
      #pragma unroll
      for (int r = 0; r < 4; ++r)
        Hlds[(q*4 + r)*LSTM_PAD + wave*16 + c] = (unsigned short)f2bf_rtn(hv[r]);
      __syncthreads();
    }
  }
}

// ---------- LayerNorm (last step) + dense [64,12]; dual-dtype store ----------
__global__ __launch_bounds__(256) void final_kernel(
    const float* __restrict__ hfin, const float* __restrict__ lng, const float* __restrict__ lnb,
    const float* __restrict__ dW, const float* __restrict__ db,
    const int* __restrict__ flag, void* __restrict__ outv){
  __shared__ float sm[4][64];
  int lane = threadIdx.x & 63, wave = threadIdx.x >> 6;
  int s = blockIdx.x*4 + wave;
  float h = hfin[(size_t)s*64 + lane];
  float mu = wave_sum(h) * (1.f/64.f);
  float dev = h - mu;
  float var = wave_sum(dev*dev) * (1.f/64.f);
  float hn = dev * rsqrtf(var + 1e-5f) * lng[lane] + lnb[lane];
  sm[wave][lane] = hn;
  __syncthreads();
  if (lane < 12){
    float o = db[lane];
    #pragma unroll
    for (int k = 0; k < 64; ++k) o = fmaf(sm[wave][k], dW[k*12 + lane], o);
    if (*flag) ((unsigned short*)outv)[(size_t)s*12 + lane] = (unsigned short)f2bf_rtn(o);
    else       ((float*)outv)[(size_t)s*12 + lane] = o;
  }
}

extern "C" void kernel_launch(void* const* d_in, const int* in_sizes, int n_in,
                              void* d_out, int out_size, void* d_ws, size_t ws_size,
                              hipStream_t stream) {
  const int* esrc = (const int*)d_in[1];
  const int* edst = (const int*)d_in[2];

  static const int sizes[19] = {768000, 512, 64, 4096, 64, 64, 64, 4096, 64, 64, 64,
                                16384, 16384, 256, 256, 64, 64, 768, 12};
  static const int srcidx[19] = {0, 3, 4, 5, 6, 7, 8, 9, 10, 11, 12,
                                 13, 14, 15, 16, 17, 18, 19, 20};
  ConvArgs ca;
  {
    int acc = 0;
    for (int i = 0; i < 19; ++i){ ca.src[i] = d_in[srcidx[i]]; ca.off[i] = acc; acc += sizes[i]; }
    ca.off[19] = acc;
  }

  float* P     = (float*)d_ws;               // [NPARAM_PAD_]
  float* bufA  = P + NPARAM_PAD_;            // xh -> gout1 -> g2out
  float* bufB  = bufA + (size_t)GNH_;        // h1 -> h2 -> hfin
  float* esb   = bufB + (size_t)GNH_;
  float* edb   = esb  + (size_t)G_*N_;
  int*   counts= (int*)(edb + (size_t)G_*N_);
  int*   cursor= counts + N_;
  int*   offs  = cursor + N_;
  int*   csrc  = offs + (N_ + 1);
  int*   flag  = csrc + E_;
  float* hfin  = bufB;

  const float* px   = P;
  const float* pfcW = P + 768000;
  const float* pfcb = P + 768512;
  const float* pg1W = P + 768576;
  const float* pg1b = P + 772672;
  const float* pg1as= P + 772736;
  const float* pg1ad= P + 772800;
  const float* pg2W = P + 772864;
  const float* pg2b = P + 776960;
  const float* pg2as= P + 777024;
  const float* pg2ad= P + 777088;
  const float* pWih = P + 777152;
  const float* pWhh = P + 793536;
  const float* pbih = P + 809920;
  const float* pbhh = P + 810176;
  const float* plng = P + 810432;
  const float* plnb = P + 810496;
  const float* pdW  = P + 810560;
  const float* pdb  = P + 811328;

  detect_kernel<<<1, 256, 0, stream>>>((const unsigned*)d_in[0], flag);
  convert_kernel<<<(NPARAM_ + 255)/256, 256, 0, stream>>>(ca, flag, P);

  fc_kernel<<<24000, 256, 0, stream>>>(px, pfcW, pfcb, bufA);

  zero_kernel<<<16, 256, 0, stream>>>(counts, 2*N_);
  count_kernel<<<(E_+255)/256, 256, 0, stream>>>(edst, counts);
  scan_kernel<<<1, 64, 0, stream>>>(counts, offs);
  fill_kernel<<<(E_+255)/256, 256, 0, stream>>>(esrc, edst, offs, cursor, csrc);

  gat_h_mfma_kernel<0><<<750, 256, 0, stream>>>(bufA, pg1W, pg1as, pg1ad, bufB, esb, edb);
  gat_agg_kernel<<<24000, 256, 0, stream>>>(bufB, esb, edb, offs, csrc, pg1b, bufA);

  gat_h_mfma_kernel<1><<<750, 256, 0, stream>>>(bufA, pg2W, pg2as, pg2ad, bufB, esb, edb);
  gat_agg_kernel<<<24000, 256, 0, stream>>>(bufB, esb, edb, offs, csrc, pg2b, bufA);

  lstm_mfma_kernel<<<250, 256, 0, stream>>>(bufA, pWih, pWhh, pbih, pbhh, hfin);
  final_kernel<<<1000, 256, 0, stream>>>(hfin, plng, plnb, pdW, pdb, flag, d_out);
}

// Round 6
// 408.257 us; speedup vs baseline: 2.6104x; 1.2583x over previous
//
#include <hip/hip_runtime.h>
#include <hip/hip_bf16.h>
#include <math.h>

#define B_   2
#define N_   2000
#define T_   24
#define NX_  8
#define H_   64
#define G_   (B_*T_)        // 48 graphs
#define E_   32000
#define BN_  (B_*N_)        // 4000 sequences
#define TH_  (T_*H_)        // 1536
#define NTH_ (N_*T_*H_)     // 3072000
#define GNH_ (G_*N_*H_)     // 6144000
#define NPARAM_ 811340      // total canonical fp32 param elements
#define NPARAM_PAD_ 811392
#define LSTM_PAD 72         // padded H-row (bf16 elems): 144B stride, 16B aligned, <=2-way banks

using bf16 = __hip_bfloat16;
typedef short bf16x8 __attribute__((ext_vector_type(8)));
typedef float f32x4  __attribute__((ext_vector_type(4)));

__device__ __forceinline__ float uasf(unsigned u){ return __uint_as_float(u); }
__device__ __forceinline__ float wave_sum(float v){
  #pragma unroll
  for (int o = 32; o > 0; o >>= 1) v += __shfl_xor(v, o, 64);
  return v;
}
__device__ __forceinline__ float wave_max(float v){
  #pragma unroll
  for (int o = 32; o > 0; o >>= 1) v = fmaxf(v, __shfl_xor(v, o, 64));
  return v;
}
__device__ __forceinline__ float fastrcp(float x){ return __builtin_amdgcn_rcpf(x); }
__device__ __forceinline__ float sigf(float x){ return fastrcp(1.f + __expf(-x)); }
__device__ __forceinline__ float tanhfast(float x){ return 1.f - 2.f*fastrcp(1.f + __expf(2.f*x)); }
__device__ __forceinline__ float gelu_exact(float x){ return 0.5f*x*(1.f + erff(x*0.70710678118654752f)); }
__device__ __forceinline__ unsigned f2bf_rtn(float f){
  unsigned u = __float_as_uint(f);
  u += 0x7fffu + ((u >> 16) & 1u);
  return u >> 16;
}
__device__ __forceinline__ bf16x8 pack8(float4 a, float4 b){
  bf16x8 v;
  v[0]=(short)f2bf_rtn(a.x); v[1]=(short)f2bf_rtn(a.y);
  v[2]=(short)f2bf_rtn(a.z); v[3]=(short)f2bf_rtn(a.w);
  v[4]=(short)f2bf_rtn(b.x); v[5]=(short)f2bf_rtn(b.y);
  v[6]=(short)f2bf_rtn(b.z); v[7]=(short)f2bf_rtn(b.w);
  return v;
}

// ---------- dtype detection: are float inputs bf16-packed or fp32? ----------
__global__ void detect_kernel(const unsigned* __restrict__ xw, int* __restrict__ flag){
  __shared__ int cnt;
  if (threadIdx.x == 0) cnt = 0;
  __syncthreads();
  int c = 0;
  for (int i = threadIdx.x; i < 4096; i += 256){
    unsigned e = (xw[i] >> 7) & 0xffu;   // bf16 exponent of lo half
    if (e >= 100u && e <= 140u) c++;
  }
  atomicAdd(&cnt, c);
  __syncthreads();
  if (threadIdx.x == 0) *flag = (cnt > 3276) ? 1 : 0;  // 1 = bf16 inputs
}

// ---------- canonicalize all float params to fp32 block ----------
struct ConvArgs {
  const void* src[19];
  int off[20];
};
__global__ __launch_bounds__(256) void convert_kernel(
    ConvArgs a, const int* __restrict__ flag, float* __restrict__ dst){
  int i = blockIdx.x*256 + threadIdx.x;
  if (i >= NPARAM_) return;
  int seg = 0;
  while (i >= a.off[seg+1]) seg++;
  int j = i - a.off[seg];
  float v;
  if (*flag){
    v = uasf(((unsigned)((const unsigned short*)a.src[seg])[j]) << 16);
  } else {
    v = ((const float*)a.src[seg])[j];
  }
  dst[i] = v;
}

// ---------- fc: x[B,N,T,8] @ W[8,64] + b -> bufA in graph layout [B,T,N,64] ----------
__global__ __launch_bounds__(256) void fc_kernel(
    const float* __restrict__ x, const float* __restrict__ W,
    const float* __restrict__ b, float* __restrict__ xh){
  int tid = blockIdx.x*256 + threadIdx.x;
  int h   = tid & 63;
  int bnt = tid >> 6;
  int t = bnt % T_;
  int n = (bnt / T_) % N_;
  int bb = bnt / (T_*N_);
  const float* xr = x + ((size_t)(bb*N_ + n)*T_ + t)*NX_;
  float s = b[h];
  #pragma unroll
  for (int k = 0; k < NX_; ++k) s = fmaf(xr[k], W[k*H_ + h], s);
  xh[((size_t)(bb*T_ + t)*N_ + n)*H_ + h] = s;
}

// ---------- CSR build ----------
__global__ void zero_kernel(int* p, int n){
  int i = blockIdx.x*256 + threadIdx.x;
  if (i < n) p[i] = 0;
}
__global__ void count_kernel(const int* __restrict__ dst, int* __restrict__ counts){
  int e = blockIdx.x*256 + threadIdx.x;
  if (e < E_) atomicAdd(&counts[dst[e]], 1);
}
__global__ void scan_kernel(const int* __restrict__ counts, int* __restrict__ offs){
  int lane = threadIdx.x & 63;
  int base = 0;
  for (int c0 = 0; c0 < N_; c0 += 64){
    int i = c0 + lane;
    int v = (i < N_) ? counts[i] : 0;
    int xv = v;
    #pragma unroll
    for (int o = 1; o < 64; o <<= 1){
      int y = __shfl_up(xv, o, 64);
      if (lane >= o) xv += y;
    }
    if (i < N_) offs[i] = base + xv - v;
    base += __shfl(xv, 63, 64);
  }
  if (lane == 0) offs[N_] = base;
}
__global__ void fill_kernel(const int* __restrict__ src, const int* __restrict__ dst,
                            const int* __restrict__ offs, int* __restrict__ cursor,
                            int* __restrict__ csrc){
  int e = blockIdx.x*256 + threadIdx.x;
  if (e >= E_) return;
  int d = dst[e];
  int pos = atomicAdd(&cursor[d], 1);
  csrc[offs[d] + pos] = src[e];
}

// ---------- GAT h = xin @ W via MFMA (h stored bf16); es = h.asrc; ed = h.adst ----------
template<int SCR>
__global__ __launch_bounds__(256) void gat_h_mfma_kernel(
    const float* __restrict__ xin, const float* __restrict__ W,
    const float* __restrict__ asrc, const float* __restrict__ adst,
    unsigned short* __restrict__ hbuf, float* __restrict__ es, float* __restrict__ ed){
  int lane = threadIdx.x & 63, wave = threadIdx.x >> 6;
  int q = lane >> 4, c = lane & 15;
  bf16x8 Bf[4][2];
  #pragma unroll
  for (int nt = 0; nt < 4; ++nt){
    #pragma unroll
    for (int ks = 0; ks < 2; ++ks){
      bf16x8 v;
      #pragma unroll
      for (int j = 0; j < 8; ++j)
        v[j] = (short)f2bf_rtn(W[(ks*32 + q*8 + j)*H_ + nt*16 + c]);
      Bf[nt][ks] = v;
    }
  }
  float aS[4], aD[4];
  #pragma unroll
  for (int nt = 0; nt < 4; ++nt){ aS[nt] = asrc[nt*16+c]; aD[nt] = adst[nt*16+c]; }

  int w = blockIdx.x*4 + wave;
  #pragma unroll
  for (int it = 0; it < 2; ++it){
    int tile = w*2 + it;
    int p0 = tile*16;
    int p  = p0 + c;
    const float* xr;
    if (SCR){
      int g = p / N_, n = p - g*N_;
      int bb = g / T_, t = g - bb*T_;
      xr = xin + (size_t)bb*NTH_ + (size_t)n*TH_ + (size_t)t*H_;
    } else {
      xr = xin + (size_t)p*H_;
    }
    const float4* xr4 = (const float4*)xr;
    float4 x0 = xr4[q*2],     x1 = xr4[q*2 + 1];
    float4 x2 = xr4[8 + q*2], x3 = xr4[8 + q*2 + 1];
    bf16x8 A0 = pack8(x0, x1);
    bf16x8 A1 = pack8(x2, x3);

    f32x4 acc[4];
    #pragma unroll
    for (int nt = 0; nt < 4; ++nt){ acc[nt][0]=0.f; acc[nt][1]=0.f; acc[nt][2]=0.f; acc[nt][3]=0.f; }
    #pragma unroll
    for (int nt = 0; nt < 4; ++nt) acc[nt] = __builtin_amdgcn_mfma_f32_16x16x32_bf16(A0, Bf[nt][0], acc[nt], 0, 0, 0);
    #pragma unroll
    for (int nt = 0; nt < 4; ++nt) acc[nt] = __builtin_amdgcn_mfma_f32_16x16x32_bf16(A1, Bf[nt][1], acc[nt], 0, 0, 0);

    #pragma unroll
    for (int nt = 0; nt < 4; ++nt){
      #pragma unroll
      for (int r = 0; r < 4; ++r)
        hbuf[(size_t)(p0 + q*4 + r)*H_ + nt*16 + c] = (unsigned short)f2bf_rtn(acc[nt][r]);
    }
    #pragma unroll
    for (int r = 0; r < 4; ++r){
      float e1 = acc[0][r]*aS[0] + acc[1][r]*aS[1] + acc[2][r]*aS[2] + acc[3][r]*aS[3];
      float e2 = acc[0][r]*aD[0] + acc[1][r]*aD[1] + acc[2][r]*aD[2] + acc[3][r]*aD[3];
      #pragma unroll
      for (int o = 8; o > 0; o >>= 1){
        e1 += __shfl_xor(e1, o, 64);
        e2 += __shfl_xor(e2, o, 64);
      }
      if (c == 0){
        es[p0 + q*4 + r] = e1;
        ed[p0 + q*4 + r] = e2;
      }
    }
  }
}

// ---------- GAT aggregate: lane-parallel softmax prologue + shfl-broadcast gather ----------
__global__ __launch_bounds__(256) void gat_agg_kernel(
    const unsigned short* __restrict__ hbuf, const float* __restrict__ es, const float* __restrict__ ed,
    const int* __restrict__ offs, const int* __restrict__ csrc,
    const float* __restrict__ bias, float* __restrict__ gout){
  int lane = threadIdx.x & 63, wave = threadIdx.x >> 6;
  int gd = blockIdx.x*4 + wave;
  int g = gd / N_, d = gd - g*N_;
  int start = offs[d], deg = offs[d+1] - start;
  const float* esg = es + (size_t)g*N_;
  float edv = ed[(size_t)g*N_ + d];
  const unsigned short* hg = hbuf + (size_t)g*N_*H_;

  float acc = 0.f;
  if (deg <= 64){
    // lanes = edges: one round-trip for csrc + scores
    int sv = 0; float sc = -1e30f;
    if (lane < deg){
      sv = csrc[start + lane];
      float e = esg[sv] + edv;
      sc = e > 0.f ? e : 0.2f*e;
    }
    float m = wave_max(sc);
    float ex = (lane < deg) ? __expf(sc - m) : 0.f;
    float ssum = wave_sum(ex);
    ex *= fastrcp(ssum + 1e-16f);
    // lanes = channels: serial loop, addresses from registers -> independent gathers
    for (int j = 0; j < deg; ++j){
      int   s  = __shfl(sv, j, 64);
      float al = __shfl(ex, j, 64);
      float hv = uasf(((unsigned)hg[(size_t)s*H_ + lane]) << 16);
      acc = fmaf(al, hv, acc);
    }
  } else {
    // general chunked path (deg > 64 is pathological for this graph)
    float m = -1e30f;
    for (int base = 0; base < deg; base += 64){
      int i = base + lane;
      if (i < deg){
        int s = csrc[start + i];
        float e = esg[s] + edv;
        float t = e > 0.f ? e : 0.2f*e;
        m = fmaxf(m, t);
      }
    }
    m = wave_max(m);
    float ssum = 0.f;
    for (int base = 0; base < deg; base += 64){
      int i = base + lane;
      if (i < deg){
        int s = csrc[start + i];
        float e = esg[s] + edv;
        float t = e > 0.f ? e : 0.2f*e;
        ssum += __expf(t - m);
      }
    }
    ssum = wave_sum(ssum);
    float inv = fastrcp(ssum + 1e-16f);
    for (int base = 0; base < deg; base += 64){
      int i = base + lane;
      int sv = 0; float ex = 0.f;
      if (i < deg){
        sv = csrc[start + i];
        float e = esg[sv] + edv;
        float t = e > 0.f ? e : 0.2f*e;
        ex = __expf(t - m) * inv;
      }
      int rem = deg - base; if (rem > 64) rem = 64;
      for (int j = 0; j < rem; ++j){
        int   s  = __shfl(sv, j, 64);
        float al = __shfl(ex, j, 64);
        float hv = uasf(((unsigned)hg[(size_t)s*H_ + lane]) << 16);
        acc = fmaf(al, hv, acc);
      }
    }
  }
  float val = gelu_exact(acc + bias[lane]);
  gout[(size_t)gd*H_ + lane] = val;
}

// ---------- LSTM via MFMA: Z = [H | X_t] @ [Whh^T ; Wih^T], K=128 fused ----------
__global__ __launch_bounds__(256) void lstm_mfma_kernel(
    const float* __restrict__ xin,   // flat [BN*T, 64]: row = seq*T + t
    const float* __restrict__ Wih,   // [256][64] row-major
    const float* __restrict__ Whh,   // [256][64] row-major
    const float* __restrict__ bih, const float* __restrict__ bhh,
    float* __restrict__ hfin){
  __shared__ __align__(16) unsigned short Hlds[16*LSTM_PAD];
  int tid = threadIdx.x;
  int lane = tid & 63, wave = tid >> 6;
  int q = lane >> 4, c = lane & 15;
  int s0 = blockIdx.x * 16;

  bf16x8 Bf[4][4];
  #pragma unroll
  for (int g = 0; g < 4; ++g){
    int n = g*64 + wave*16 + c;
    #pragma unroll
    for (int ks = 0; ks < 4; ++ks){
      const float* srcp = (ks < 2) ? (Whh + (size_t)n*64 + ks*32 + q*8)
                                   : (Wih + (size_t)n*64 + (ks-2)*32 + q*8);
      float4 a = ((const float4*)srcp)[0];
      float4 b = ((const float4*)srcp)[1];
      Bf[g][ks] = pack8(a, b);
    }
  }
  float bsum[4];
  #pragma unroll
  for (int g = 0; g < 4; ++g){
    int n = g*64 + wave*16 + c;
    bsum[g] = bih[n] + bhh[n];
  }
  for (int i = tid; i < 16*LSTM_PAD; i += 256) Hlds[i] = 0;
  float cst[4] = {0.f, 0.f, 0.f, 0.f};
  __syncthreads();

  for (int t = 0; t < T_; ++t){
    const float4* xr4 = (const float4*)(xin + ((size_t)(s0 + c)*T_ + t)*64);
    float4 x0 = xr4[q*2],     x1 = xr4[q*2 + 1];
    float4 x2 = xr4[8 + q*2], x3 = xr4[8 + q*2 + 1];
    bf16x8 Ax0 = pack8(x0, x1);
    bf16x8 Ax1 = pack8(x2, x3);
    const bf16x8* hrow = (const bf16x8*)(Hlds + c*LSTM_PAD);
    bf16x8 Ah0 = hrow[q];
    bf16x8 Ah1 = hrow[4 + q];

    f32x4 acc[4];
    #pragma unroll
    for (int g = 0; g < 4; ++g){ acc[g][0]=bsum[g]; acc[g][1]=bsum[g]; acc[g][2]=bsum[g]; acc[g][3]=bsum[g]; }
    #pragma unroll
    for (int g = 0; g < 4; ++g) acc[g] = __builtin_amdgcn_mfma_f32_16x16x32_bf16(Ah0, Bf[g][0], acc[g], 0, 0, 0);
    #pragma unroll
    for (int g = 0; g < 4; ++g) acc[g] = __builtin_amdgcn_mfma_f32_16x16x32_bf16(Ah1, Bf[g][1], acc[g], 0, 0, 0);
    #pragma unroll
    for (int g = 0; g < 4; ++g) acc[g] = __builtin_amdgcn_mfma_f32_16x16x32_bf16(Ax0, Bf[g][2], acc[g], 0, 0, 0);
    #pragma unroll
    for (int g = 0; g < 4; ++g) acc[g] = __builtin_amdgcn_mfma_f32_16x16x32_bf16(Ax1, Bf[g][3], acc[g], 0, 0, 0);

    float hv[4];
    #pragma unroll
    for (int r = 0; r < 4; ++r){
      float zi = acc[0][r], zf = acc[1][r], zg = acc[2][r], zo = acc[3][r];
      cst[r] = sigf(zf)*cst[r] + sigf(zi)*tanhfast(zg);
      hv[r] = sigf(zo)*tanhfast(cst[r]);
    }
    if (t == T_-1){
      #pragma unroll
      for (int r = 0; r < 4; ++r)
        hfin[(size_t)(s0 + q*4 + r)*64 + wave*16 + c] = hv[r];
    } else {
      __syncthreads();
      #pragma unroll
      for (int r = 0; r < 4; ++r)
        Hlds[(q*4 + r)*LSTM_PAD + wave*16 + c] = (unsigned short)f2bf_rtn(hv[r]);
      __syncthreads();
    }
  }
}

// ---------- LayerNorm (last step) + dense [64,12]; dual-dtype store ----------
__global__ __launch_bounds__(256) void final_kernel(
    const float* __restrict__ hfin, const float* __restrict__ lng, const float* __restrict__ lnb,
    const float* __restrict__ dW, const float* __restrict__ db,
    const int* __restrict__ flag, void* __restrict__ outv){
  __shared__ float sm[4][64];
  int lane = threadIdx.x & 63, wave = threadIdx.x >> 6;
  int s = blockIdx.x*4 + wave;
  float h = hfin[(size_t)s*64 + lane];
  float mu = wave_sum(h) * (1.f/64.f);
  float dev = h - mu;
  float var = wave_sum(dev*dev) * (1.f/64.f);
  float hn = dev * rsqrtf(var + 1e-5f) * lng[lane] + lnb[lane];
  sm[wave][lane] = hn;
  __syncthreads();
  if (lane < 12){
    float o = db[lane];
    #pragma unroll
    for (int k = 0; k < 64; ++k) o = fmaf(sm[wave][k], dW[k*12 + lane], o);
    if (*flag) ((unsigned short*)outv)[(size_t)s*12 + lane] = (unsigned short)f2bf_rtn(o);
    else       ((float*)outv)[(size_t)s*12 + lane] = o;
  }
}

extern "C" void kernel_launch(void* const* d_in, const int* in_sizes, int n_in,
                              void* d_out, int out_size, void* d_ws, size_t ws_size,
                              hipStream_t stream) {
  const int* esrc = (const int*)d_in[1];
  const int* edst = (const int*)d_in[2];

  static const int sizes[19] = {768000, 512, 64, 4096, 64, 64, 64, 4096, 64, 64, 64,
                                16384, 16384, 256, 256, 64, 64, 768, 12};
  static const int srcidx[19] = {0, 3, 4, 5, 6, 7, 8, 9, 10, 11, 12,
                                 13, 14, 15, 16, 17, 18, 19, 20};
  ConvArgs ca;
  {
    int acc = 0;
    for (int i = 0; i < 19; ++i){ ca.src[i] = d_in[srcidx[i]]; ca.off[i] = acc; acc += sizes[i]; }
    ca.off[19] = acc;
  }

  float* P     = (float*)d_ws;               // [NPARAM_PAD_]
  float* bufA  = P + NPARAM_PAD_;            // xh -> gout1 -> g2out
  float* bufB  = bufA + (size_t)GNH_;        // hbuf(bf16) -> hfin(f32)
  float* esb   = bufB + (size_t)GNH_;
  float* edb   = esb  + (size_t)G_*N_;
  int*   counts= (int*)(edb + (size_t)G_*N_);
  int*   cursor= counts + N_;
  int*   offs  = cursor + N_;
  int*   csrc  = offs + (N_ + 1);
  int*   flag  = csrc + E_;
  unsigned short* hbuf = (unsigned short*)bufB;
  float* hfin  = bufB;                       // alias (hbuf dead after agg#2)

  const float* px   = P;
  const float* pfcW = P + 768000;
  const float* pfcb = P + 768512;
  const float* pg1W = P + 768576;
  const float* pg1b = P + 772672;
  const float* pg1as= P + 772736;
  const float* pg1ad= P + 772800;
  const float* pg2W = P + 772864;
  const float* pg2b = P + 776960;
  const float* pg2as= P + 777024;
  const float* pg2ad= P + 777088;
  const float* pWih = P + 777152;
  const float* pWhh = P + 793536;
  const float* pbih = P + 809920;
  const float* pbhh = P + 810176;
  const float* plng = P + 810432;
  const float* plnb = P + 810496;
  const float* pdW  = P + 810560;
  const float* pdb  = P + 811328;

  detect_kernel<<<1, 256, 0, stream>>>((const unsigned*)d_in[0], flag);
  convert_kernel<<<(NPARAM_ + 255)/256, 256, 0, stream>>>(ca, flag, P);

  fc_kernel<<<24000, 256, 0, stream>>>(px, pfcW, pfcb, bufA);

  zero_kernel<<<16, 256, 0, stream>>>(counts, 2*N_);
  count_kernel<<<(E_+255)/256, 256, 0, stream>>>(edst, counts);
  scan_kernel<<<1, 64, 0, stream>>>(counts, offs);
  fill_kernel<<<(E_+255)/256, 256, 0, stream>>>(esrc, edst, offs, cursor, csrc);

  gat_h_mfma_kernel<0><<<750, 256, 0, stream>>>(bufA, pg1W, pg1as, pg1ad, hbuf, esb, edb);
  gat_agg_kernel<<<24000, 256, 0, stream>>>(hbuf, esb, edb, offs, csrc, pg1b, bufA);

  gat_h_mfma_kernel<1><<<750, 256, 0, stream>>>(bufA, pg2W, pg2as, pg2ad, hbuf, esb, edb);
  gat_agg_kernel<<<24000, 256, 0, stream>>>(hbuf, esb, edb, offs, csrc, pg2b, bufA);

  lstm_mfma_kernel<<<250, 256, 0, stream>>>(bufA, pWih, pWhh, pbih, pbhh, hfin);
  final_kernel<<<1000, 256, 0, stream>>>(hfin, plng, plnb, pdW, pdb, flag, d_out);
}

// Round 7
// 323.687 us; speedup vs baseline: 3.2924x; 1.2613x over previous
//
#include <hip/hip_runtime.h>
#include <hip/hip_bf16.h>
#include <math.h>

#define B_   2
#define N_   2000
#define T_   24
#define NX_  8
#define H_   64
#define G_   (B_*T_)        // 48 graphs
#define E_   32000
#define BN_  (B_*N_)        // 4000 sequences
#define TH_  (T_*H_)        // 1536
#define NTH_ (N_*T_*H_)     // 3072000
#define GNH_ (G_*N_*H_)     // 6144000
#define NPARAM_ 811340      // total canonical fp32 param elements
#define NPARAM_PAD_ 811392
#define LSTM_PAD 72         // padded H-row (bf16 elems): 144B stride, 16B aligned, <=2-way banks

using bf16 = __hip_bfloat16;
typedef short bf16x8 __attribute__((ext_vector_type(8)));
typedef float f32x4  __attribute__((ext_vector_type(4)));

__device__ __forceinline__ float uasf(unsigned u){ return __uint_as_float(u); }
__device__ __forceinline__ float wave_sum(float v){
  #pragma unroll
  for (int o = 32; o > 0; o >>= 1) v += __shfl_xor(v, o, 64);
  return v;
}
__device__ __forceinline__ float wave_max(float v){
  #pragma unroll
  for (int o = 32; o > 0; o >>= 1) v = fmaxf(v, __shfl_xor(v, o, 64));
  return v;
}
__device__ __forceinline__ float fastrcp(float x){ return __builtin_amdgcn_rcpf(x); }
__device__ __forceinline__ float sigf(float x){ return fastrcp(1.f + __expf(-x)); }
__device__ __forceinline__ float tanhfast(float x){ return 1.f - 2.f*fastrcp(1.f + __expf(2.f*x)); }
__device__ __forceinline__ float gelu_exact(float x){ return 0.5f*x*(1.f + erff(x*0.70710678118654752f)); }
__device__ __forceinline__ unsigned f2bf_rtn(float f){
  unsigned u = __float_as_uint(f);
  u += 0x7fffu + ((u >> 16) & 1u);
  return u >> 16;
}
__device__ __forceinline__ bf16x8 pack8(float4 a, float4 b){
  bf16x8 v;
  v[0]=(short)f2bf_rtn(a.x); v[1]=(short)f2bf_rtn(a.y);
  v[2]=(short)f2bf_rtn(a.z); v[3]=(short)f2bf_rtn(a.w);
  v[4]=(short)f2bf_rtn(b.x); v[5]=(short)f2bf_rtn(b.y);
  v[6]=(short)f2bf_rtn(b.z); v[7]=(short)f2bf_rtn(b.w);
  return v;
}

// ---------- dtype detection: are float inputs bf16-packed or fp32? ----------
__global__ void detect_kernel(const unsigned* __restrict__ xw, int* __restrict__ flag){
  __shared__ int cnt;
  if (threadIdx.x == 0) cnt = 0;
  __syncthreads();
  int c = 0;
  for (int i = threadIdx.x; i < 4096; i += 256){
    unsigned e = (xw[i] >> 7) & 0xffu;   // bf16 exponent of lo half
    if (e >= 100u && e <= 140u) c++;
  }
  atomicAdd(&cnt, c);
  __syncthreads();
  if (threadIdx.x == 0) *flag = (cnt > 3276) ? 1 : 0;  // 1 = bf16 inputs
}

// ---------- canonicalize all float params to fp32 block ----------
struct ConvArgs {
  const void* src[19];
  int off[20];
};
__global__ __launch_bounds__(256) void convert_kernel(
    ConvArgs a, const int* __restrict__ flag, float* __restrict__ dst){
  int i = blockIdx.x*256 + threadIdx.x;
  if (i >= NPARAM_) return;
  int seg = 0;
  while (i >= a.off[seg+1]) seg++;
  int j = i - a.off[seg];
  float v;
  if (*flag){
    v = uasf(((unsigned)((const unsigned short*)a.src[seg])[j]) << 16);
  } else {
    v = ((const float*)a.src[seg])[j];
  }
  dst[i] = v;
}

// ---------- fc: x[B,N,T,8] @ W[8,64] + b -> bufA in graph layout [B,T,N,64] ----------
__global__ __launch_bounds__(256) void fc_kernel(
    const float* __restrict__ x, const float* __restrict__ W,
    const float* __restrict__ b, float* __restrict__ xh){
  int tid = blockIdx.x*256 + threadIdx.x;
  int h   = tid & 63;
  int bnt = tid >> 6;
  int t = bnt % T_;
  int n = (bnt / T_) % N_;
  int bb = bnt / (T_*N_);
  const float* xr = x + ((size_t)(bb*N_ + n)*T_ + t)*NX_;
  float s = b[h];
  #pragma unroll
  for (int k = 0; k < NX_; ++k) s = fmaf(xr[k], W[k*H_ + h], s);
  xh[((size_t)(bb*T_ + t)*N_ + n)*H_ + h] = s;
}

// ---------- CSR build ----------
__global__ void zero_kernel(int* p, int n){
  int i = blockIdx.x*256 + threadIdx.x;
  if (i < n) p[i] = 0;
}
__global__ void count_kernel(const int* __restrict__ dst, int* __restrict__ counts){
  int e = blockIdx.x*256 + threadIdx.x;
  if (e < E_) atomicAdd(&counts[dst[e]], 1);
}
__global__ void scan_kernel(const int* __restrict__ counts, int* __restrict__ offs){
  int lane = threadIdx.x & 63;
  int base = 0;
  for (int c0 = 0; c0 < N_; c0 += 64){
    int i = c0 + lane;
    int v = (i < N_) ? counts[i] : 0;
    int xv = v;
    #pragma unroll
    for (int o = 1; o < 64; o <<= 1){
      int y = __shfl_up(xv, o, 64);
      if (lane >= o) xv += y;
    }
    if (i < N_) offs[i] = base + xv - v;
    base += __shfl(xv, 63, 64);
  }
  if (lane == 0) offs[N_] = base;
}
__global__ void fill_kernel(const int* __restrict__ src, const int* __restrict__ dst,
                            const int* __restrict__ offs, int* __restrict__ cursor,
                            int* __restrict__ csrc){
  int e = blockIdx.x*256 + threadIdx.x;
  if (e >= E_) return;
  int d = dst[e];
  int pos = atomicAdd(&cursor[d], 1);
  csrc[offs[d] + pos] = src[e];
}

// ---------- GAT h = xin @ W via MFMA (h stored bf16); es = h.asrc; ed = h.adst ----------
template<int SCR>
__global__ __launch_bounds__(256) void gat_h_mfma_kernel(
    const float* __restrict__ xin, const float* __restrict__ W,
    const float* __restrict__ asrc, const float* __restrict__ adst,
    unsigned short* __restrict__ hbuf, float* __restrict__ es, float* __restrict__ ed){
  int lane = threadIdx.x & 63, wave = threadIdx.x >> 6;
  int q = lane >> 4, c = lane & 15;
  bf16x8 Bf[4][2];
  #pragma unroll
  for (int nt = 0; nt < 4; ++nt){
    #pragma unroll
    for (int ks = 0; ks < 2; ++ks){
      bf16x8 v;
      #pragma unroll
      for (int j = 0; j < 8; ++j)
        v[j] = (short)f2bf_rtn(W[(ks*32 + q*8 + j)*H_ + nt*16 + c]);
      Bf[nt][ks] = v;
    }
  }
  float aS[4], aD[4];
  #pragma unroll
  for (int nt = 0; nt < 4; ++nt){ aS[nt] = asrc[nt*16+c]; aD[nt] = adst[nt*16+c]; }

  int w = blockIdx.x*4 + wave;
  #pragma unroll
  for (int it = 0; it < 2; ++it){
    int tile = w*2 + it;
    int p0 = tile*16;
    int p  = p0 + c;
    const float* xr;
    if (SCR){
      int g = p / N_, n = p - g*N_;
      int bb = g / T_, t = g - bb*T_;
      xr = xin + (size_t)bb*NTH_ + (size_t)n*TH_ + (size_t)t*H_;
    } else {
      xr = xin + (size_t)p*H_;
    }
    const float4* xr4 = (const float4*)xr;
    float4 x0 = xr4[q*2],     x1 = xr4[q*2 + 1];
    float4 x2 = xr4[8 + q*2], x3 = xr4[8 + q*2 + 1];
    bf16x8 A0 = pack8(x0, x1);
    bf16x8 A1 = pack8(x2, x3);

    f32x4 acc[4];
    #pragma unroll
    for (int nt = 0; nt < 4; ++nt){ acc[nt][0]=0.f; acc[nt][1]=0.f; acc[nt][2]=0.f; acc[nt][3]=0.f; }
    #pragma unroll
    for (int nt = 0; nt < 4; ++nt) acc[nt] = __builtin_amdgcn_mfma_f32_16x16x32_bf16(A0, Bf[nt][0], acc[nt], 0, 0, 0);
    #pragma unroll
    for (int nt = 0; nt < 4; ++nt) acc[nt] = __builtin_amdgcn_mfma_f32_16x16x32_bf16(A1, Bf[nt][1], acc[nt], 0, 0, 0);

    #pragma unroll
    for (int nt = 0; nt < 4; ++nt){
      #pragma unroll
      for (int r = 0; r < 4; ++r)
        hbuf[(size_t)(p0 + q*4 + r)*H_ + nt*16 + c] = (unsigned short)f2bf_rtn(acc[nt][r]);
    }
    #pragma unroll
    for (int r = 0; r < 4; ++r){
      float e1 = acc[0][r]*aS[0] + acc[1][r]*aS[1] + acc[2][r]*aS[2] + acc[3][r]*aS[3];
      float e2 = acc[0][r]*aD[0] + acc[1][r]*aD[1] + acc[2][r]*aD[2] + acc[3][r]*aD[3];
      #pragma unroll
      for (int o = 8; o > 0; o >>= 1){
        e1 += __shfl_xor(e1, o, 64);
        e2 += __shfl_xor(e2, o, 64);
      }
      if (c == 0){
        es[p0 + q*4 + r] = e1;
        ed[p0 + q*4 + r] = e2;
      }
    }
  }
}

// ---------- GAT aggregate: lane-parallel softmax + unrolled-chunk gather ----------
__global__ __launch_bounds__(256) void gat_agg_kernel(
    const unsigned short* __restrict__ hbuf, const float* __restrict__ es, const float* __restrict__ ed,
    const int* __restrict__ offs, const int* __restrict__ csrc,
    const float* __restrict__ bias, float* __restrict__ gout){
  int lane = threadIdx.x & 63, wave = threadIdx.x >> 6;
  int gd = blockIdx.x*4 + wave;
  int g = gd / N_, d = gd - g*N_;
  int start = offs[d], deg = offs[d+1] - start;
  const float* esg = es + (size_t)g*N_;
  float edv = ed[(size_t)g*N_ + d];
  const unsigned short* hg = hbuf + (size_t)g*N_*H_;

  float acc = 0.f;
  if (deg <= 64){
    // lanes = edges: one round-trip for csrc + scores
    int sv = 0; float sc = -1e30f;
    if (lane < deg){
      sv = csrc[start + lane];
      float e = esg[sv] + edv;
      sc = e > 0.f ? e : 0.2f*e;
    }
    float m = wave_max(sc);
    float ex = (lane < deg) ? __expf(sc - m) : 0.f;
    float ssum = wave_sum(ex);
    ex *= fastrcp(ssum + 1e-16f);
    // chunk-of-8 unrolled gather: shfls first, 8 independent loads, then fmas
    for (int j0 = 0; j0 < deg; j0 += 8){
      int ss[8]; float aa[8];
      #pragma unroll
      for (int u = 0; u < 8; ++u){
        int j = j0 + u;
        int jj = (j < deg) ? j : 0;
        ss[u] = __shfl(sv, jj, 64);
        float a = __shfl(ex, jj, 64);
        aa[u] = (j < deg) ? a : 0.f;
      }
      float hv[8];
      #pragma unroll
      for (int u = 0; u < 8; ++u)
        hv[u] = uasf(((unsigned)hg[(size_t)ss[u]*H_ + lane]) << 16);
      #pragma unroll
      for (int u = 0; u < 8; ++u) acc = fmaf(aa[u], hv[u], acc);
    }
  } else {
    // general chunked path (deg > 64 is pathological for this graph)
    float m = -1e30f;
    for (int base = 0; base < deg; base += 64){
      int i = base + lane;
      if (i < deg){
        int s = csrc[start + i];
        float e = esg[s] + edv;
        float t = e > 0.f ? e : 0.2f*e;
        m = fmaxf(m, t);
      }
    }
    m = wave_max(m);
    float ssum = 0.f;
    for (int base = 0; base < deg; base += 64){
      int i = base + lane;
      if (i < deg){
        int s = csrc[start + i];
        float e = esg[s] + edv;
        float t = e > 0.f ? e : 0.2f*e;
        ssum += __expf(t - m);
      }
    }
    ssum = wave_sum(ssum);
    float inv = fastrcp(ssum + 1e-16f);
    for (int base = 0; base < deg; base += 64){
      int i = base + lane;
      int sv = 0; float ex = 0.f;
      if (i < deg){
        sv = csrc[start + i];
        float e = esg[sv] + edv;
        float t = e > 0.f ? e : 0.2f*e;
        ex = __expf(t - m) * inv;
      }
      int rem = deg - base; if (rem > 64) rem = 64;
      for (int j0 = 0; j0 < rem; j0 += 8){
        int ss[8]; float aa[8];
        #pragma unroll
        for (int u = 0; u < 8; ++u){
          int j = j0 + u;
          int jj = (j < rem) ? j : 0;
          ss[u] = __shfl(sv, jj, 64);
          float a = __shfl(ex, jj, 64);
          aa[u] = (j < rem) ? a : 0.f;
        }
        float hv[8];
        #pragma unroll
        for (int u = 0; u < 8; ++u)
          hv[u] = uasf(((unsigned)hg[(size_t)ss[u]*H_ + lane]) << 16);
        #pragma unroll
        for (int u = 0; u < 8; ++u) acc = fmaf(aa[u], hv[u], acc);
      }
    }
  }
  float val = gelu_exact(acc + bias[lane]);
  gout[(size_t)gd*H_ + lane] = val;
}

// ---------- LSTM via MFMA: Z = [H | X_t] @ [Whh^T ; Wih^T], K=128 fused ----------
__global__ __launch_bounds__(256) void lstm_mfma_kernel(
    const float* __restrict__ xin,   // flat [BN*T, 64]: row = seq*T + t
    const float* __restrict__ Wih,   // [256][64] row-major
    const float* __restrict__ Whh,   // [256][64] row-major
    const float* __restrict__ bih, const float* __restrict__ bhh,
    float* __restrict__ hfin){
  __shared__ __align__(16) unsigned short Hlds[16*LSTM_PAD];
  int tid = threadIdx.x;
  int lane = tid & 63, wave = tid >> 6;
  int q = lane >> 4, c = lane & 15;
  int s0 = blockIdx.x * 16;

  bf16x8 Bf[4][4];
  #pragma unroll
  for (int g = 0; g < 4; ++g){
    int n = g*64 + wave*16 + c;
    #pragma unroll
    for (int ks = 0; ks < 4; ++ks){
      const float* srcp = (ks < 2) ? (Whh + (size_t)n*64 + ks*32 + q*8)
                                   : (Wih + (size_t)n*64 + (ks-2)*32 + q*8);
      float4 a = ((const float4*)srcp)[0];
      float4 b = ((const float4*)srcp)[1];
      Bf[g][ks] = pack8(a, b);
    }
  }
  float bsum[4];
  #pragma unroll
  for (int g = 0; g < 4; ++g){
    int n = g*64 + wave*16 + c;
    bsum[g] = bih[n] + bhh[n];
  }
  for (int i = tid; i < 16*LSTM_PAD; i += 256) Hlds[i] = 0;
  float cst[4] = {0.f, 0.f, 0.f, 0.f};
  __syncthreads();

  for (int t = 0; t < T_; ++t){
    const float4* xr4 = (const float4*)(xin + ((size_t)(s0 + c)*T_ + t)*64);
    float4 x0 = xr4[q*2],     x1 = xr4[q*2 + 1];
    float4 x2 = xr4[8 + q*2], x3 = xr4[8 + q*2 + 1];
    bf16x8 Ax0 = pack8(x0, x1);
    bf16x8 Ax1 = pack8(x2, x3);
    const bf16x8* hrow = (const bf16x8*)(Hlds + c*LSTM_PAD);
    bf16x8 Ah0 = hrow[q];
    bf16x8 Ah1 = hrow[4 + q];

    f32x4 acc[4];
    #pragma unroll
    for (int g = 0; g < 4; ++g){ acc[g][0]=bsum[g]; acc[g][1]=bsum[g]; acc[g][2]=bsum[g]; acc[g][3]=bsum[g]; }
    #pragma unroll
    for (int g = 0; g < 4; ++g) acc[g] = __builtin_amdgcn_mfma_f32_16x16x32_bf16(Ah0, Bf[g][0], acc[g], 0, 0, 0);
    #pragma unroll
    for (int g = 0; g < 4; ++g) acc[g] = __builtin_amdgcn_mfma_f32_16x16x32_bf16(Ah1, Bf[g][1], acc[g], 0, 0, 0);
    #pragma unroll
    for (int g = 0; g < 4; ++g) acc[g] = __builtin_amdgcn_mfma_f32_16x16x32_bf16(Ax0, Bf[g][2], acc[g], 0, 0, 0);
    #pragma unroll
    for (int g = 0; g < 4; ++g) acc[g] = __builtin_amdgcn_mfma_f32_16x16x32_bf16(Ax1, Bf[g][3], acc[g], 0, 0, 0);

    float hv[4];
    #pragma unroll
    for (int r = 0; r < 4; ++r){
      float zi = acc[0][r], zf = acc[1][r], zg = acc[2][r], zo = acc[3][r];
      cst[r] = sigf(zf)*cst[r] + sigf(zi)*tanhfast(zg);
      hv[r] = sigf(zo)*tanhfast(cst[r]);
    }
    if (t == T_-1){
      #pragma unroll
      for (int r = 0; r < 4; ++r)
        hfin[(size_t)(s0 + q*4 + r)*64 + wave*16 + c] = hv[r];
    } else {
      __syncthreads();
      #pragma unroll
      for (int r = 0; r < 4; ++r)
        Hlds[(q*4 + r)*LSTM_PAD + wave*16 + c] = (unsigned short)f2bf_rtn(hv[r]);
      __syncthreads();
    }
  }
}

// ---------- LayerNorm (last step) + dense [64,12]; dual-dtype store ----------
__global__ __launch_bounds__(256) void final_kernel(
    const float* __restrict__ hfin, const float* __restrict__ lng, const float* __restrict__ lnb,
    const float* __restrict__ dW, const float* __restrict__ db,
    const int* __restrict__ flag, void* __restrict__ outv){
  __shared__ float sm[4][64];
  int lane = threadIdx.x & 63, wave = threadIdx.x >> 6;
  int s = blockIdx.x*4 + wave;
  float h = hfin[(size_t)s*64 + lane];
  float mu = wave_sum(h) * (1.f/64.f);
  float dev = h - mu;
  float var = wave_sum(dev*dev) * (1.f/64.f);
  float hn = dev * rsqrtf(var + 1e-5f) * lng[lane] + lnb[lane];
  sm[wave][lane] = hn;
  __syncthreads();
  if (lane < 12){
    float o = db[lane];
    #pragma unroll
    for (int k = 0; k < 64; ++k) o = fmaf(sm[wave][k], dW[k*12 + lane], o);
    if (*flag) ((unsigned short*)outv)[(size_t)s*12 + lane] = (unsigned short)f2bf_rtn(o);
    else       ((float*)outv)[(size_t)s*12 + lane] = o;
  }
}

extern "C" void kernel_launch(void* const* d_in, const int* in_sizes, int n_in,
                              void* d_out, int out_size, void* d_ws, size_t ws_size,
                              hipStream_t stream) {
  const int* esrc = (const int*)d_in[1];
  const int* edst = (const int*)d_in[2];

  static const int sizes[19] = {768000, 512, 64, 4096, 64, 64, 64, 4096, 64, 64, 64,
                                16384, 16384, 256, 256, 64, 64, 768, 12};
  static const int srcidx[19] = {0, 3, 4, 5, 6, 7, 8, 9, 10, 11, 12,
                                 13, 14, 15, 16, 17, 18, 19, 20};
  ConvArgs ca;
  {
    int acc = 0;
    for (int i = 0; i < 19; ++i){ ca.src[i] = d_in[srcidx[i]]; ca.off[i] = acc; acc += sizes[i]; }
    ca.off[19] = acc;
  }

  float* P     = (float*)d_ws;               // [NPARAM_PAD_]
  float* bufA  = P + NPARAM_PAD_;            // xh -> gout1 -> g2out
  float* bufB  = bufA + (size_t)GNH_;        // hbuf(bf16) -> hfin(f32)
  float* esb   = bufB + (size_t)GNH_;
  float* edb   = esb  + (size_t)G_*N_;
  int*   counts= (int*)(edb + (size_t)G_*N_);
  int*   cursor= counts + N_;
  int*   offs  = cursor + N_;
  int*   csrc  = offs + (N_ + 1);
  int*   flag  = csrc + E_;
  unsigned short* hbuf = (unsigned short*)bufB;
  float* hfin  = bufB;                       // alias (hbuf dead after agg#2)

  const float* px   = P;
  const float* pfcW = P + 768000;
  const float* pfcb = P + 768512;
  const float* pg1W = P + 768576;
  const float* pg1b = P + 772672;
  const float* pg1as= P + 772736;
  const float* pg1ad= P + 772800;
  const float* pg2W = P + 772864;
  const float* pg2b = P + 776960;
  const float* pg2as= P + 777024;
  const float* pg2ad= P + 777088;
  const float* pWih = P + 777152;
  const float* pWhh = P + 793536;
  const float* pbih = P + 809920;
  const float* pbhh = P + 810176;
  const float* plng = P + 810432;
  const float* plnb = P + 810496;
  const float* pdW  = P + 810560;
  const float* pdb  = P + 811328;

  detect_kernel<<<1, 256, 0, stream>>>((const unsigned*)d_in[0], flag);
  convert_kernel<<<(NPARAM_ + 255)/256, 256, 0, stream>>>(ca, flag, P);

  fc_kernel<<<24000, 256, 0, stream>>>(px, pfcW, pfcb, bufA);

  zero_kernel<<<16, 256, 0, stream>>>(counts, 2*N_);
  count_kernel<<<(E_+255)/256, 256, 0, stream>>>(edst, counts);
  scan_kernel<<<1, 64, 0, stream>>>(counts, offs);
  fill_kernel<<<(E_+255)/256, 256, 0, stream>>>(esrc, edst, offs, cursor, csrc);

  gat_h_mfma_kernel<0><<<750, 256, 0, stream>>>(bufA, pg1W, pg1as, pg1ad, hbuf, esb, edb);
  gat_agg_kernel<<<24000, 256, 0, stream>>>(hbuf, esb, edb, offs, csrc, pg1b, bufA);

  gat_h_mfma_kernel<1><<<750, 256, 0, stream>>>(bufA, pg2W, pg2as, pg2ad, hbuf, esb, edb);
  gat_agg_kernel<<<24000, 256, 0, stream>>>(hbuf, esb, edb, offs, csrc, pg2b, bufA);

  lstm_mfma_kernel<<<250, 256, 0, stream>>>(bufA, pWih, pWhh, pbih, pbhh, hfin);
  final_kernel<<<1000, 256, 0, stream>>>(hfin, plng, plnb, pdW, pdb, flag, d_out);
}

// Round 8
// 307.826 us; speedup vs baseline: 3.4620x; 1.0515x over previous
//
#include <hip/hip_runtime.h>
#include <hip/hip_bf16.h>
#include <math.h>

#define B_   2
#define N_   2000
#define T_   24
#define NX_  8
#define H_   64
#define G_   (B_*T_)        // 48 graphs
#define E_   32000
#define BN_  (B_*N_)        // 4000 sequences
#define TH_  (T_*H_)        // 1536
#define NTH_ (N_*T_*H_)     // 3072000
#define GNH_ (G_*N_*H_)     // 6144000
#define NPARAM_ 811340      // total canonical fp32 param elements
#define NPARAM_PAD_ 811392
#define LSTM_PAD 72         // padded H-row (bf16 elems): 144B stride, 16B aligned, <=2-way banks

using bf16 = __hip_bfloat16;
typedef short bf16x8 __attribute__((ext_vector_type(8)));
typedef float f32x4  __attribute__((ext_vector_type(4)));

__device__ __forceinline__ float uasf(unsigned u){ return __uint_as_float(u); }
__device__ __forceinline__ float wave_sum(float v){
  #pragma unroll
  for (int o = 32; o > 0; o >>= 1) v += __shfl_xor(v, o, 64);
  return v;
}
__device__ __forceinline__ float wave_max(float v){
  #pragma unroll
  for (int o = 32; o > 0; o >>= 1) v = fmaxf(v, __shfl_xor(v, o, 64));
  return v;
}
__device__ __forceinline__ float fastrcp(float x){ return __builtin_amdgcn_rcpf(x); }
__device__ __forceinline__ float sigf(float x){ return fastrcp(1.f + __expf(-x)); }
__device__ __forceinline__ float tanhfast(float x){ return 1.f - 2.f*fastrcp(1.f + __expf(2.f*x)); }
__device__ __forceinline__ float gelu_exact(float x){ return 0.5f*x*(1.f + erff(x*0.70710678118654752f)); }
__device__ __forceinline__ unsigned f2bf_rtn(float f){
  unsigned u = __float_as_uint(f);
  u += 0x7fffu + ((u >> 16) & 1u);
  return u >> 16;
}
__device__ __forceinline__ bf16x8 pack8(float4 a, float4 b){
  bf16x8 v;
  v[0]=(short)f2bf_rtn(a.x); v[1]=(short)f2bf_rtn(a.y);
  v[2]=(short)f2bf_rtn(a.z); v[3]=(short)f2bf_rtn(a.w);
  v[4]=(short)f2bf_rtn(b.x); v[5]=(short)f2bf_rtn(b.y);
  v[6]=(short)f2bf_rtn(b.z); v[7]=(short)f2bf_rtn(b.w);
  return v;
}

// ---------- dtype detection: are float inputs bf16-packed or fp32? ----------
__global__ void detect_kernel(const unsigned* __restrict__ xw, int* __restrict__ flag){
  __shared__ int cnt;
  if (threadIdx.x == 0) cnt = 0;
  __syncthreads();
  int c = 0;
  for (int i = threadIdx.x; i < 4096; i += 256){
    unsigned e = (xw[i] >> 7) & 0xffu;   // bf16 exponent of lo half
    if (e >= 100u && e <= 140u) c++;
  }
  atomicAdd(&cnt, c);
  __syncthreads();
  if (threadIdx.x == 0) *flag = (cnt > 3276) ? 1 : 0;  // 1 = bf16 inputs
}

// ---------- canonicalize all float params to fp32 block ----------
struct ConvArgs {
  const void* src[19];
  int off[20];
};
__global__ __launch_bounds__(256) void convert_kernel(
    ConvArgs a, const int* __restrict__ flag, float* __restrict__ dst){
  int i = blockIdx.x*256 + threadIdx.x;
  if (i >= NPARAM_) return;
  int seg = 0;
  while (i >= a.off[seg+1]) seg++;
  int j = i - a.off[seg];
  float v;
  if (*flag){
    v = uasf(((unsigned)((const unsigned short*)a.src[seg])[j]) << 16);
  } else {
    v = ((const float*)a.src[seg])[j];
  }
  dst[i] = v;
}

// ---------- fold fc into GAT1: Wc = fcW @ g1W [8,64], bc = fcb @ g1W [64] ----------
__global__ void wc_kernel(const float* __restrict__ fcW, const float* __restrict__ fcb,
                          const float* __restrict__ g1W,
                          float* __restrict__ wc, float* __restrict__ bc){
  int tid = threadIdx.x;            // 512 threads
  int i = tid >> 6, n = tid & 63;
  float s = 0.f;
  #pragma unroll 8
  for (int k = 0; k < 64; ++k) s = fmaf(fcW[i*64 + k], g1W[k*64 + n], s);
  wc[i*64 + n] = s;
  if (i == 0){
    float b = 0.f;
    #pragma unroll 8
    for (int k = 0; k < 64; ++k) b = fmaf(fcb[k], g1W[k*64 + n], b);
    bc[n] = b;
  }
}

// ---------- CSR build ----------
__global__ void zero_kernel(int* p, int n){
  int i = blockIdx.x*256 + threadIdx.x;
  if (i < n) p[i] = 0;
}
__global__ void count_kernel(const int* __restrict__ dst, int* __restrict__ counts){
  int e = blockIdx.x*256 + threadIdx.x;
  if (e < E_) atomicAdd(&counts[dst[e]], 1);
}
__global__ void scan_kernel(const int* __restrict__ counts, int* __restrict__ offs){
  int lane = threadIdx.x & 63;
  int base = 0;
  for (int c0 = 0; c0 < N_; c0 += 64){
    int i = c0 + lane;
    int v = (i < N_) ? counts[i] : 0;
    int xv = v;
    #pragma unroll
    for (int o = 1; o < 64; o <<= 1){
      int y = __shfl_up(xv, o, 64);
      if (lane >= o) xv += y;
    }
    if (i < N_) offs[i] = base + xv - v;
    base += __shfl(xv, 63, 64);
  }
  if (lane == 0) offs[N_] = base;
}
__global__ void fill_kernel(const int* __restrict__ src, const int* __restrict__ dst,
                            const int* __restrict__ offs, int* __restrict__ cursor,
                            int* __restrict__ csrc){
  int e = blockIdx.x*256 + threadIdx.x;
  if (e >= E_) return;
  int d = dst[e];
  int pos = atomicAdd(&cursor[d], 1);
  csrc[offs[d] + pos] = src[e];
}

// ---------- GAT1 fused: h = x @ Wc + bc via MFMA (K=8 in K=32 slot) ----------
// Tile = 16 rows p0..p0+15 (125 tiles/graph exactly -> g uniform per tile).
__global__ __launch_bounds__(256) void gat_h1_fused_kernel(
    const float* __restrict__ x, const float* __restrict__ wc, const float* __restrict__ bc,
    const float* __restrict__ asrc, const float* __restrict__ adst,
    unsigned short* __restrict__ hbuf, float* __restrict__ es, float* __restrict__ ed){
  int lane = threadIdx.x & 63, wave = threadIdx.x >> 6;
  int q = lane >> 4, c = lane & 15;
  bf16x8 Bf[4];                       // B[n=c][k=q*8+j]; only q==0 rows of Wc nonzero
  #pragma unroll
  for (int nt = 0; nt < 4; ++nt){
    bf16x8 v;
    #pragma unroll
    for (int j = 0; j < 8; ++j)
      v[j] = (q == 0) ? (short)f2bf_rtn(wc[j*64 + nt*16 + c]) : (short)0;
    Bf[nt] = v;
  }
  float bcv[4];
  #pragma unroll
  for (int nt = 0; nt < 4; ++nt) bcv[nt] = bc[nt*16 + c];
  float aS[4], aD[4];
  #pragma unroll
  for (int nt = 0; nt < 4; ++nt){ aS[nt] = asrc[nt*16+c]; aD[nt] = adst[nt*16+c]; }

  int w = blockIdx.x*4 + wave;        // 750*4 = 3000 waves, 2 tiles each
  #pragma unroll
  for (int it = 0; it < 2; ++it){
    int tile = w*2 + it;
    int p0 = tile*16;
    int g  = p0 / N_, n0 = p0 - g*N_;
    int bb = g / T_,  tt = g - bb*T_;
    bf16x8 A0;
    #pragma unroll
    for (int j = 0; j < 8; ++j) A0[j] = 0;
    if (q == 0){
      const float4* xr4 = (const float4*)(x + ((size_t)(bb*N_ + n0 + c)*T_ + tt)*NX_);
      A0 = pack8(xr4[0], xr4[1]);
    }
    f32x4 acc[4];
    #pragma unroll
    for (int nt = 0; nt < 4; ++nt){ acc[nt][0]=bcv[nt]; acc[nt][1]=bcv[nt]; acc[nt][2]=bcv[nt]; acc[nt][3]=bcv[nt]; }
    #pragma unroll
    for (int nt = 0; nt < 4; ++nt) acc[nt] = __builtin_amdgcn_mfma_f32_16x16x32_bf16(A0, Bf[nt], acc[nt], 0, 0, 0);

    #pragma unroll
    for (int nt = 0; nt < 4; ++nt){
      #pragma unroll
      for (int r = 0; r < 4; ++r)
        hbuf[(size_t)(p0 + q*4 + r)*H_ + nt*16 + c] = (unsigned short)f2bf_rtn(acc[nt][r]);
    }
    #pragma unroll
    for (int r = 0; r < 4; ++r){
      float e1 = acc[0][r]*aS[0] + acc[1][r]*aS[1] + acc[2][r]*aS[2] + acc[3][r]*aS[3];
      float e2 = acc[0][r]*aD[0] + acc[1][r]*aD[1] + acc[2][r]*aD[2] + acc[3][r]*aD[3];
      #pragma unroll
      for (int o = 8; o > 0; o >>= 1){
        e1 += __shfl_xor(e1, o, 64);
        e2 += __shfl_xor(e2, o, 64);
      }
      if (c == 0){
        es[p0 + q*4 + r] = e1;
        ed[p0 + q*4 + r] = e2;
      }
    }
  }
}

// ---------- GAT2 h = gout1 @ W via MFMA (scrambled raw-reshape reads) ----------
__global__ __launch_bounds__(256) void gat_h2_mfma_kernel(
    const float* __restrict__ xin, const float* __restrict__ W,
    const float* __restrict__ asrc, const float* __restrict__ adst,
    unsigned short* __restrict__ hbuf, float* __restrict__ es, float* __restrict__ ed){
  int lane = threadIdx.x & 63, wave = threadIdx.x >> 6;
  int q = lane >> 4, c = lane & 15;
  bf16x8 Bf[4][2];
  #pragma unroll
  for (int nt = 0; nt < 4; ++nt){
    #pragma unroll
    for (int ks = 0; ks < 2; ++ks){
      bf16x8 v;
      #pragma unroll
      for (int j = 0; j < 8; ++j)
        v[j] = (short)f2bf_rtn(W[(ks*32 + q*8 + j)*H_ + nt*16 + c]);
      Bf[nt][ks] = v;
    }
  }
  float aS[4], aD[4];
  #pragma unroll
  for (int nt = 0; nt < 4; ++nt){ aS[nt] = asrc[nt*16+c]; aD[nt] = adst[nt*16+c]; }

  int w = blockIdx.x*4 + wave;
  #pragma unroll
  for (int it = 0; it < 2; ++it){
    int tile = w*2 + it;
    int p0 = tile*16;
    int p  = p0 + c;
    int g = p / N_, n = p - g*N_;
    int bb = g / T_, t = g - bb*T_;
    const float4* xr4 = (const float4*)(xin + (size_t)bb*NTH_ + (size_t)n*TH_ + (size_t)t*H_);
    float4 x0 = xr4[q*2],     x1 = xr4[q*2 + 1];
    float4 x2 = xr4[8 + q*2], x3 = xr4[8 + q*2 + 1];
    bf16x8 A0 = pack8(x0, x1);
    bf16x8 A1 = pack8(x2, x3);

    f32x4 acc[4];
    #pragma unroll
    for (int nt = 0; nt < 4; ++nt){ acc[nt][0]=0.f; acc[nt][1]=0.f; acc[nt][2]=0.f; acc[nt][3]=0.f; }
    #pragma unroll
    for (int nt = 0; nt < 4; ++nt) acc[nt] = __builtin_amdgcn_mfma_f32_16x16x32_bf16(A0, Bf[nt][0], acc[nt], 0, 0, 0);
    #pragma unroll
    for (int nt = 0; nt < 4; ++nt) acc[nt] = __builtin_amdgcn_mfma_f32_16x16x32_bf16(A1, Bf[nt][1], acc[nt], 0, 0, 0);

    #pragma unroll
    for (int nt = 0; nt < 4; ++nt){
      #pragma unroll
      for (int r = 0; r < 4; ++r)
        hbuf[(size_t)(p0 + q*4 + r)*H_ + nt*16 + c] = (unsigned short)f2bf_rtn(acc[nt][r]);
    }
    #pragma unroll
    for (int r = 0; r < 4; ++r){
      float e1 = acc[0][r]*aS[0] + acc[1][r]*aS[1] + acc[2][r]*aS[2] + acc[3][r]*aS[3];
      float e2 = acc[0][r]*aD[0] + acc[1][r]*aD[1] + acc[2][r]*aD[2] + acc[3][r]*aD[3];
      #pragma unroll
      for (int o = 8; o > 0; o >>= 1){
        e1 += __shfl_xor(e1, o, 64);
        e2 += __shfl_xor(e2, o, 64);
      }
      if (c == 0){
        es[p0 + q*4 + r] = e1;
        ed[p0 + q*4 + r] = e2;
      }
    }
  }
}

// ---------- GAT aggregate: packed (alpha<<16|src) single-shfl gather ----------
__global__ __launch_bounds__(256) void gat_agg_kernel(
    const unsigned short* __restrict__ hbuf, const float* __restrict__ es, const float* __restrict__ ed,
    const int* __restrict__ offs, const int* __restrict__ csrc,
    const float* __restrict__ bias, float* __restrict__ gout){
  int lane = threadIdx.x & 63, wave = threadIdx.x >> 6;
  int gd = blockIdx.x*4 + wave;
  int g = gd / N_, d = gd - g*N_;
  int start = offs[d], deg = offs[d+1] - start;
  const float* esg = es + (size_t)g*N_;
  float edv = ed[(size_t)g*N_ + d];
  const char* hg = (const char*)(hbuf + (size_t)g*N_*H_);
  unsigned lanoff = ((unsigned)lane) << 1;

  float acc = 0.f;
  if (deg <= 64){
    int sv = 0; float sc = -1e30f;
    if (lane < deg){
      sv = csrc[start + lane];
      float e = esg[sv] + edv;
      sc = e > 0.f ? e : 0.2f*e;
    }
    float m = wave_max(sc);
    float ex = (lane < deg) ? __expf(sc - m) : 0.f;
    float ssum = wave_sum(ex);
    ex *= fastrcp(ssum + 1e-16f);
    unsigned pw = (f2bf_rtn(ex) << 16) | (unsigned)sv;   // alpha(bf16) | src_id
    for (int j0 = 0; j0 < deg; j0 += 8){
      unsigned wv[8]; float aa[8]; unsigned off[8];
      #pragma unroll
      for (int u = 0; u < 8; ++u){
        int j = j0 + u;
        int jj = (j < deg) ? j : 0;
        wv[u] = (unsigned)__shfl((int)pw, jj, 64);
        aa[u] = (j < deg) ? uasf(wv[u] & 0xffff0000u) : 0.f;
        off[u] = ((wv[u] & 0xffffu) << 7) + lanoff;
      }
      float hv[8];
      #pragma unroll
      for (int u = 0; u < 8; ++u)
        hv[u] = uasf(((unsigned)*(const unsigned short*)(hg + off[u])) << 16);
      #pragma unroll
      for (int u = 0; u < 8; ++u) acc = fmaf(aa[u], hv[u], acc);
    }
  } else {
    // general chunked path (deg > 64 is pathological for this graph)
    float m = -1e30f;
    for (int base = 0; base < deg; base += 64){
      int i = base + lane;
      if (i < deg){
        int s = csrc[start + i];
        float e = esg[s] + edv;
        float t = e > 0.f ? e : 0.2f*e;
        m = fmaxf(m, t);
      }
    }
    m = wave_max(m);
    float ssum = 0.f;
    for (int base = 0; base < deg; base += 64){
      int i = base + lane;
      if (i < deg){
        int s = csrc[start + i];
        float e = esg[s] + edv;
        float t = e > 0.f ? e : 0.2f*e;
        ssum += __expf(t - m);
      }
    }
    ssum = wave_sum(ssum);
    float inv = fastrcp(ssum + 1e-16f);
    for (int base = 0; base < deg; base += 64){
      int i = base + lane;
      int sv = 0; float ex = 0.f;
      if (i < deg){
        sv = csrc[start + i];
        float e = esg[sv] + edv;
        float t = e > 0.f ? e : 0.2f*e;
        ex = __expf(t - m) * inv;
      }
      unsigned pw = (f2bf_rtn(ex) << 16) | (unsigned)sv;
      int rem = deg - base; if (rem > 64) rem = 64;
      for (int j0 = 0; j0 < rem; j0 += 8){
        unsigned wv[8]; float aa[8]; unsigned off[8];
        #pragma unroll
        for (int u = 0; u < 8; ++u){
          int j = j0 + u;
          int jj = (j < rem) ? j : 0;
          wv[u] = (unsigned)__shfl((int)pw, jj, 64);
          aa[u] = (j < rem) ? uasf(wv[u] & 0xffff0000u) : 0.f;
          off[u] = ((wv[u] & 0xffffu) << 7) + lanoff;
        }
        float hv[8];
        #pragma unroll
        for (int u = 0; u < 8; ++u)
          hv[u] = uasf(((unsigned)*(const unsigned short*)(hg + off[u])) << 16);
        #pragma unroll
        for (int u = 0; u < 8; ++u) acc = fmaf(aa[u], hv[u], acc);
      }
    }
  }
  float val = gelu_exact(acc + bias[lane]);
  gout[(size_t)gd*H_ + lane] = val;
}

// ---------- LSTM via MFMA: Z = [H | X_t] @ [Whh^T ; Wih^T], K=128 fused ----------
__global__ __launch_bounds__(256) void lstm_mfma_kernel(
    const float* __restrict__ xin,   // flat [BN*T, 64]: row = seq*T + t
    const float* __restrict__ Wih,   // [256][64] row-major
    const float* __restrict__ Whh,   // [256][64] row-major
    const float* __restrict__ bih, const float* __restrict__ bhh,
    float* __restrict__ hfin){
  __shared__ __align__(16) unsigned short Hlds[16*LSTM_PAD];
  int tid = threadIdx.x;
  int lane = tid & 63, wave = tid >> 6;
  int q = lane >> 4, c = lane & 15;
  int s0 = blockIdx.x * 16;

  bf16x8 Bf[4][4];
  #pragma unroll
  for (int g = 0; g < 4; ++g){
    int n = g*64 + wave*16 + c;
    #pragma unroll
    for (int ks = 0; ks < 4; ++ks){
      const float* srcp = (ks < 2) ? (Whh + (size_t)n*64 + ks*32 + q*8)
                                   : (Wih + (size_t)n*64 + (ks-2)*32 + q*8);
      float4 a = ((const float4*)srcp)[0];
      float4 b = ((const float4*)srcp)[1];
      Bf[g][ks] = pack8(a, b);
    }
  }
  float bsum[4];
  #pragma unroll
  for (int g = 0; g < 4; ++g){
    int n = g*64 + wave*16 + c;
    bsum[g] = bih[n] + bhh[n];
  }
  for (int i = tid; i < 16*LSTM_PAD; i += 256) Hlds[i] = 0;
  float cst[4] = {0.f, 0.f, 0.f, 0.f};
  __syncthreads();

  for (int t = 0; t < T_; ++t){
    const float4* xr4 = (const float4*)(xin + ((size_t)(s0 + c)*T_ + t)*64);
    float4 x0 = xr4[q*2],     x1 = xr4[q*2 + 1];
    float4 x2 = xr4[8 + q*2], x3 = xr4[8 + q*2 + 1];
    bf16x8 Ax0 = pack8(x0, x1);
    bf16x8 Ax1 = pack8(x2, x3);
    const bf16x8* hrow = (const bf16x8*)(Hlds + c*LSTM_PAD);
    bf16x8 Ah0 = hrow[q];
    bf16x8 Ah1 = hrow[4 + q];

    f32x4 acc[4];
    #pragma unroll
    for (int g = 0; g < 4; ++g){ acc[g][0]=bsum[g]; acc[g][1]=bsum[g]; acc[g][2]=bsum[g]; acc[g][3]=bsum[g]; }
    #pragma unroll
    for (int g = 0; g < 4; ++g) acc[g] = __builtin_amdgcn_mfma_f32_16x16x32_bf16(Ah0, Bf[g][0], acc[g], 0, 0, 0);
    #pragma unroll
    for (int g = 0; g < 4; ++g) acc[g] = __builtin_amdgcn_mfma_f32_16x16x32_bf16(Ah1, Bf[g][1], acc[g], 0, 0, 0);
    #pragma unroll
    for (int g = 0; g < 4; ++g) acc[g] = __builtin_amdgcn_mfma_f32_16x16x32_bf16(Ax0, Bf[g][2], acc[g], 0, 0, 0);
    #pragma unroll
    for (int g = 0; g < 4; ++g) acc[g] = __builtin_amdgcn_mfma_f32_16x16x32_bf16(Ax1, Bf[g][3], acc[g], 0, 0, 0);

    float hv[4];
    #pragma unroll
    for (int r = 0; r < 4; ++r){
      float zi = acc[0][r], zf = acc[1][r], zg = acc[2][r], zo = acc[3][r];
      cst[r] = sigf(zf)*cst[r] + sigf(zi)*tanhfast(zg);
      hv[r] = sigf(zo)*tanhfast(cst[r]);
    }
    if (t == T_-1){
      #pragma unroll
      for (int r = 0; r < 4; ++r)
        hfin[(size_t)(s0 + q*4 + r)*64 + wave*16 + c] = hv[r];
    } else {
      __syncthreads();
      #pragma unroll
      for (int r = 0; r < 4; ++r)
        Hlds[(q*4 + r)*LSTM_PAD + wave*16 + c] = (unsigned short)f2bf_rtn(hv[r]);
      __syncthreads();
    }
  }
}

// ---------- LayerNorm (last step) + dense [64,12]; dual-dtype store ----------
__global__ __launch_bounds__(256) void final_kernel(
    const float* __restrict__ hfin, const float* __restrict__ lng, const float* __restrict__ lnb,
    const float* __restrict__ dW, const float* __restrict__ db,
    const int* __restrict__ flag, void* __restrict__ outv){
  __shared__ float sm[4][64];
  int lane = threadIdx.x & 63, wave = threadIdx.x >> 6;
  int s = blockIdx.x*4 + wave;
  float h = hfin[(size_t)s*64 + lane];
  float mu = wave_sum(h) * (1.f/64.f);
  float dev = h - mu;
  float var = wave_sum(dev*dev) * (1.f/64.f);
  float hn = dev * rsqrtf(var + 1e-5f) * lng[lane] + lnb[lane];
  sm[wave][lane] = hn;
  __syncthreads();
  if (lane < 12){
    float o = db[lane];
    #pragma unroll
    for (int k = 0; k < 64; ++k) o = fmaf(sm[wave][k], dW[k*12 + lane], o);
    if (*flag) ((unsigned short*)outv)[(size_t)s*12 + lane] = (unsigned short)f2bf_rtn(o);
    else       ((float*)outv)[(size_t)s*12 + lane] = o;
  }
}

extern "C" void kernel_launch(void* const* d_in, const int* in_sizes, int n_in,
                              void* d_out, int out_size, void* d_ws, size_t ws_size,
                              hipStream_t stream) {
  const int* esrc = (const int*)d_in[1];
  const int* edst = (const int*)d_in[2];

  static const int sizes[19] = {768000, 512, 64, 4096, 64, 64, 64, 4096, 64, 64, 64,
                                16384, 16384, 256, 256, 64, 64, 768, 12};
  static const int srcidx[19] = {0, 3, 4, 5, 6, 7, 8, 9, 10, 11, 12,
                                 13, 14, 15, 16, 17, 18, 19, 20};
  ConvArgs ca;
  {
    int acc = 0;
    for (int i = 0; i < 19; ++i){ ca.src[i] = d_in[srcidx[i]]; ca.off[i] = acc; acc += sizes[i]; }
    ca.off[19] = acc;
  }

  float* P     = (float*)d_ws;               // [NPARAM_PAD_]
  float* bufA  = P + NPARAM_PAD_;            // gout1 -> g2out
  float* bufB  = bufA + (size_t)GNH_;        // hbuf(bf16) -> hfin(f32)
  float* esb   = bufB + (size_t)GNH_;
  float* edb   = esb  + (size_t)G_*N_;
  int*   counts= (int*)(edb + (size_t)G_*N_);
  int*   cursor= counts + N_;
  int*   offs  = cursor + N_;
  int*   csrc  = offs + (N_ + 1);
  int*   flag  = csrc + E_;
  float* wcb   = (float*)(flag + 1);         // Wc[512] + bc[64]
  unsigned short* hbuf = (unsigned short*)bufB;
  float* hfin  = bufB;                       // alias (hbuf dead after agg#2)

  const float* px   = P;
  const float* pfcW = P + 768000;
  const float* pfcb = P + 768512;
  const float* pg1W = P + 768576;
  const float* pg1b = P + 772672;
  const float* pg1as= P + 772736;
  const float* pg1ad= P + 772800;
  const float* pg2W = P + 772864;
  const float* pg2b = P + 776960;
  const float* pg2as= P + 777024;
  const float* pg2ad= P + 777088;
  const float* pWih = P + 777152;
  const float* pWhh = P + 793536;
  const float* pbih = P + 809920;
  const float* pbhh = P + 810176;
  const float* plng = P + 810432;
  const float* plnb = P + 810496;
  const float* pdW  = P + 810560;
  const float* pdb  = P + 811328;

  detect_kernel<<<1, 256, 0, stream>>>((const unsigned*)d_in[0], flag);
  convert_kernel<<<(NPARAM_ + 255)/256, 256, 0, stream>>>(ca, flag, P);
  wc_kernel<<<1, 512, 0, stream>>>(pfcW, pfcb, pg1W, wcb, wcb + 512);

  zero_kernel<<<16, 256, 0, stream>>>(counts, 2*N_);
  count_kernel<<<(E_+255)/256, 256, 0, stream>>>(edst, counts);
  scan_kernel<<<1, 64, 0, stream>>>(counts, offs);
  fill_kernel<<<(E_+255)/256, 256, 0, stream>>>(esrc, edst, offs, cursor, csrc);

  gat_h1_fused_kernel<<<750, 256, 0, stream>>>(px, wcb, wcb + 512, pg1as, pg1ad, hbuf, esb, edb);
  gat_agg_kernel<<<24000, 256, 0, stream>>>(hbuf, esb, edb, offs, csrc, pg1b, bufA);

  gat_h2_mfma_kernel<<<750, 256, 0, stream>>>(bufA, pg2W, pg2as, pg2ad, hbuf, esb, edb);
  gat_agg_kernel<<<24000, 256, 0, stream>>>(hbuf, esb, edb, offs, csrc, pg2b, bufA);

  lstm_mfma_kernel<<<250, 256, 0, stream>>>(bufA, pWih, pWhh, pbih, pbhh, hfin);
  final_kernel<<<1000, 256, 0, stream>>>(hfin, plng, plnb, pdW, pdb, flag, d_out);
}

// Round 9
// 266.555 us; speedup vs baseline: 3.9980x; 1.1548x over previous
//
#include <hip/hip_runtime.h>
#include <hip/hip_bf16.h>
#include <math.h>

#define B_   2
#define N_   2000
#define T_   24
#define NX_  8
#define H_   64
#define G_   (B_*T_)        // 48 graphs
#define E_   32000
#define BN_  (B_*N_)        // 4000 sequences
#define TH_  (T_*H_)        // 1536
#define NTH_ (N_*T_*H_)     // 3072000
#define GNH_ (G_*N_*H_)     // 6144000
#define NPARAM_ 43340       // canonical fp32 param elements (x excluded)
#define NPARAM_PAD_ 43392
#define LSTM_PAD 72         // padded H-row (bf16 elems): 144B stride, 16B aligned, <=2-way banks

using bf16 = __hip_bfloat16;
typedef short bf16x8 __attribute__((ext_vector_type(8)));
typedef float f32x4  __attribute__((ext_vector_type(4)));

__device__ __forceinline__ float uasf(unsigned u){ return __uint_as_float(u); }
__device__ __forceinline__ float wave_sum(float v){
  #pragma unroll
  for (int o = 32; o > 0; o >>= 1) v += __shfl_xor(v, o, 64);
  return v;
}
__device__ __forceinline__ float half_sum(float v){
  #pragma unroll
  for (int o = 16; o > 0; o >>= 1) v += __shfl_xor(v, o, 64);
  return v;
}
__device__ __forceinline__ float half_max(float v){
  #pragma unroll
  for (int o = 16; o > 0; o >>= 1) v = fmaxf(v, __shfl_xor(v, o, 64));
  return v;
}
__device__ __forceinline__ float fastrcp(float x){ return __builtin_amdgcn_rcpf(x); }
__device__ __forceinline__ float sigf(float x){ return fastrcp(1.f + __expf(-x)); }
__device__ __forceinline__ float tanhfast(float x){ return 1.f - 2.f*fastrcp(1.f + __expf(2.f*x)); }
__device__ __forceinline__ float gelu_exact(float x){ return 0.5f*x*(1.f + erff(x*0.70710678118654752f)); }
__device__ __forceinline__ unsigned f2bf_rtn(float f){
  unsigned u = __float_as_uint(f);
  u += 0x7fffu + ((u >> 16) & 1u);
  return u >> 16;
}
__device__ __forceinline__ bf16x8 pack8(float4 a, float4 b){
  bf16x8 v;
  v[0]=(short)f2bf_rtn(a.x); v[1]=(short)f2bf_rtn(a.y);
  v[2]=(short)f2bf_rtn(a.z); v[3]=(short)f2bf_rtn(a.w);
  v[4]=(short)f2bf_rtn(b.x); v[5]=(short)f2bf_rtn(b.y);
  v[6]=(short)f2bf_rtn(b.z); v[7]=(short)f2bf_rtn(b.w);
  return v;
}

// ---------- dtype detection: are float inputs bf16-packed or fp32? ----------
__global__ void detect_kernel(const unsigned* __restrict__ xw, int* __restrict__ flag){
  __shared__ int cnt;
  if (threadIdx.x == 0) cnt = 0;
  __syncthreads();
  int c = 0;
  for (int i = threadIdx.x; i < 4096; i += 256){
    unsigned e = (xw[i] >> 7) & 0xffu;   // bf16 exponent of lo half
    if (e >= 100u && e <= 140u) c++;
  }
  atomicAdd(&cnt, c);
  __syncthreads();
  if (threadIdx.x == 0) *flag = (cnt > 3276) ? 1 : 0;  // 1 = bf16 inputs
}

// ---------- canonicalize float params (not x) to fp32 block ----------
struct ConvArgs {
  const void* src[18];
  int off[19];
};
__global__ __launch_bounds__(256) void convert_kernel(
    ConvArgs a, const int* __restrict__ flag, float* __restrict__ dst){
  int i = blockIdx.x*256 + threadIdx.x;
  if (i >= NPARAM_) return;
  int seg = 0;
  while (i >= a.off[seg+1]) seg++;
  int j = i - a.off[seg];
  float v;
  if (*flag){
    v = uasf(((unsigned)((const unsigned short*)a.src[seg])[j]) << 16);
  } else {
    v = ((const float*)a.src[seg])[j];
  }
  dst[i] = v;
}

// ---------- fold fc into GAT1: Wc = fcW @ g1W [8,64], bc = fcb @ g1W [64] ----------
__global__ void wc_kernel(const float* __restrict__ fcW, const float* __restrict__ fcb,
                          const float* __restrict__ g1W,
                          float* __restrict__ wc, float* __restrict__ bc){
  int tid = threadIdx.x;            // 512 threads
  int i = tid >> 6, n = tid & 63;
  float s = 0.f;
  #pragma unroll 8
  for (int k = 0; k < 64; ++k) s = fmaf(fcW[i*64 + k], g1W[k*64 + n], s);
  wc[i*64 + n] = s;
  if (i == 0){
    float b = 0.f;
    #pragma unroll 8
    for (int k = 0; k < 64; ++k) b = fmaf(fcb[k], g1W[k*64 + n], b);
    bc[n] = b;
  }
}

// ---------- CSR build ----------
__global__ void zero_kernel(int* p, int n){
  int i = blockIdx.x*256 + threadIdx.x;
  if (i < n) p[i] = 0;
}
__global__ void count_kernel(const int* __restrict__ dst, int* __restrict__ counts){
  int e = blockIdx.x*256 + threadIdx.x;
  if (e < E_) atomicAdd(&counts[dst[e]], 1);
}
__global__ void scan_kernel(const int* __restrict__ counts, int* __restrict__ offs){
  int lane = threadIdx.x & 63;
  int base = 0;
  for (int c0 = 0; c0 < N_; c0 += 64){
    int i = c0 + lane;
    int v = (i < N_) ? counts[i] : 0;
    int xv = v;
    #pragma unroll
    for (int o = 1; o < 64; o <<= 1){
      int y = __shfl_up(xv, o, 64);
      if (lane >= o) xv += y;
    }
    if (i < N_) offs[i] = base + xv - v;
    base += __shfl(xv, 63, 64);
  }
  if (lane == 0) offs[N_] = base;
}
__global__ void fill_kernel(const int* __restrict__ src, const int* __restrict__ dst,
                            const int* __restrict__ offs, int* __restrict__ cursor,
                            int* __restrict__ csrc){
  int e = blockIdx.x*256 + threadIdx.x;
  if (e >= E_) return;
  int d = dst[e];
  int pos = atomicAdd(&cursor[d], 1);
  csrc[offs[d] + pos] = src[e];
}

// ---------- GAT1 fused: h = x @ Wc + bc via MFMA (K=8 in K=32 slot) ----------
__global__ __launch_bounds__(256) void gat_h1_fused_kernel(
    const void* __restrict__ xraw, const int* __restrict__ flag,
    const float* __restrict__ wc, const float* __restrict__ bc,
    const float* __restrict__ asrc, const float* __restrict__ adst,
    unsigned short* __restrict__ hbuf, float* __restrict__ es, float* __restrict__ ed){
  int lane = threadIdx.x & 63, wave = threadIdx.x >> 6;
  int q = lane >> 4, c = lane & 15;
  int isbf = *flag;
  bf16x8 Bf[4];                       // B[n=c][k=q*8+j]; only q==0 rows of Wc nonzero
  #pragma unroll
  for (int nt = 0; nt < 4; ++nt){
    bf16x8 v;
    #pragma unroll
    for (int j = 0; j < 8; ++j)
      v[j] = (q == 0) ? (short)f2bf_rtn(wc[j*64 + nt*16 + c]) : (short)0;
    Bf[nt] = v;
  }
  float bcv[4];
  #pragma unroll
  for (int nt = 0; nt < 4; ++nt) bcv[nt] = bc[nt*16 + c];
  float aS[4], aD[4];
  #pragma unroll
  for (int nt = 0; nt < 4; ++nt){ aS[nt] = asrc[nt*16+c]; aD[nt] = adst[nt*16+c]; }

  int w = blockIdx.x*4 + wave;        // 750*4 = 3000 waves, 2 tiles each
  #pragma unroll
  for (int it = 0; it < 2; ++it){
    int tile = w*2 + it;
    int p0 = tile*16;
    int g  = p0 / N_, n0 = p0 - g*N_;
    int bb = g / T_,  tt = g - bb*T_;
    bf16x8 A0;
    #pragma unroll
    for (int j = 0; j < 8; ++j) A0[j] = 0;
    if (q == 0){
      size_t rowelt = ((size_t)(bb*N_ + n0 + c)*T_ + tt)*NX_;
      if (isbf){
        A0 = *(const bf16x8*)((const unsigned short*)xraw + rowelt);
      } else {
        const float4* xr4 = (const float4*)((const float*)xraw + rowelt);
        A0 = pack8(xr4[0], xr4[1]);
      }
    }
    f32x4 acc[4];
    #pragma unroll
    for (int nt = 0; nt < 4; ++nt){ acc[nt][0]=bcv[nt]; acc[nt][1]=bcv[nt]; acc[nt][2]=bcv[nt]; acc[nt][3]=bcv[nt]; }
    #pragma unroll
    for (int nt = 0; nt < 4; ++nt) acc[nt] = __builtin_amdgcn_mfma_f32_16x16x32_bf16(A0, Bf[nt], acc[nt], 0, 0, 0);

    #pragma unroll
    for (int nt = 0; nt < 4; ++nt){
      #pragma unroll
      for (int r = 0; r < 4; ++r)
        hbuf[(size_t)(p0 + q*4 + r)*H_ + nt*16 + c] = (unsigned short)f2bf_rtn(acc[nt][r]);
    }
    #pragma unroll
    for (int r = 0; r < 4; ++r){
      float e1 = acc[0][r]*aS[0] + acc[1][r]*aS[1] + acc[2][r]*aS[2] + acc[3][r]*aS[3];
      float e2 = acc[0][r]*aD[0] + acc[1][r]*aD[1] + acc[2][r]*aD[2] + acc[3][r]*aD[3];
      #pragma unroll
      for (int o = 8; o > 0; o >>= 1){
        e1 += __shfl_xor(e1, o, 64);
        e2 += __shfl_xor(e2, o, 64);
      }
      if (c == 0){
        es[p0 + q*4 + r] = e1;
        ed[p0 + q*4 + r] = e2;
      }
    }
  }
}

// ---------- GAT2 h = gout1 @ W via MFMA (scrambled raw-reshape reads) ----------
__global__ __launch_bounds__(256) void gat_h2_mfma_kernel(
    const float* __restrict__ xin, const float* __restrict__ W,
    const float* __restrict__ asrc, const float* __restrict__ adst,
    unsigned short* __restrict__ hbuf, float* __restrict__ es, float* __restrict__ ed){
  int lane = threadIdx.x & 63, wave = threadIdx.x >> 6;
  int q = lane >> 4, c = lane & 15;
  bf16x8 Bf[4][2];
  #pragma unroll
  for (int nt = 0; nt < 4; ++nt){
    #pragma unroll
    for (int ks = 0; ks < 2; ++ks){
      bf16x8 v;
      #pragma unroll
      for (int j = 0; j < 8; ++j)
        v[j] = (short)f2bf_rtn(W[(ks*32 + q*8 + j)*H_ + nt*16 + c]);
      Bf[nt][ks] = v;
    }
  }
  float aS[4], aD[4];
  #pragma unroll
  for (int nt = 0; nt < 4; ++nt){ aS[nt] = asrc[nt*16+c]; aD[nt] = adst[nt*16+c]; }

  int w = blockIdx.x*4 + wave;
  #pragma unroll
  for (int it = 0; it < 2; ++it){
    int tile = w*2 + it;
    int p0 = tile*16;
    int p  = p0 + c;
    int g = p / N_, n = p - g*N_;
    int bb = g / T_, t = g - bb*T_;
    const float4* xr4 = (const float4*)(xin + (size_t)bb*NTH_ + (size_t)n*TH_ + (size_t)t*H_);
    float4 x0 = xr4[q*2],     x1 = xr4[q*2 + 1];
    float4 x2 = xr4[8 + q*2], x3 = xr4[8 + q*2 + 1];
    bf16x8 A0 = pack8(x0, x1);
    bf16x8 A1 = pack8(x2, x3);

    f32x4 acc[4];
    #pragma unroll
    for (int nt = 0; nt < 4; ++nt){ acc[nt][0]=0.f; acc[nt][1]=0.f; acc[nt][2]=0.f; acc[nt][3]=0.f; }
    #pragma unroll
    for (int nt = 0; nt < 4; ++nt) acc[nt] = __builtin_amdgcn_mfma_f32_16x16x32_bf16(A0, Bf[nt][0], acc[nt], 0, 0, 0);
    #pragma unroll
    for (int nt = 0; nt < 4; ++nt) acc[nt] = __builtin_amdgcn_mfma_f32_16x16x32_bf16(A1, Bf[nt][1], acc[nt], 0, 0, 0);

    #pragma unroll
    for (int nt = 0; nt < 4; ++nt){
      #pragma unroll
      for (int r = 0; r < 4; ++r)
        hbuf[(size_t)(p0 + q*4 + r)*H_ + nt*16 + c] = (unsigned short)f2bf_rtn(acc[nt][r]);
    }
    #pragma unroll
    for (int r = 0; r < 4; ++r){
      float e1 = acc[0][r]*aS[0] + acc[1][r]*aS[1] + acc[2][r]*aS[2] + acc[3][r]*aS[3];
      float e2 = acc[0][r]*aD[0] + acc[1][r]*aD[1] + acc[2][r]*aD[2] + acc[3][r]*aD[3];
      #pragma unroll
      for (int o = 8; o > 0; o >>= 1){
        e1 += __shfl_xor(e1, o, 64);
        e2 += __shfl_xor(e2, o, 64);
      }
      if (c == 0){
        es[p0 + q*4 + r] = e1;
        ed[p0 + q*4 + r] = e2;
      }
    }
  }
}

// ---------- GAT aggregate: 2 (g,d) per wave, 2 channels/lane, dword gathers ----------
__global__ __launch_bounds__(256) void gat_agg_kernel(
    const unsigned short* __restrict__ hbuf, const float* __restrict__ es, const float* __restrict__ ed,
    const int* __restrict__ offs, const int* __restrict__ csrc,
    const float* __restrict__ bias, float* __restrict__ gout){
  int lane = threadIdx.x & 63, wave = threadIdx.x >> 6;
  int h = lane >> 5, ln = lane & 31;
  int gd = (blockIdx.x*4 + wave)*2 + h;   // 12000 blocks -> 96000 pairs
  int g = gd / N_, d = gd - g*N_;
  int start = offs[d], deg = offs[d+1] - start;
  const float* esg = es + (size_t)g*N_;
  float edv = ed[(size_t)g*N_ + d];
  const char* hg = (const char*)(hbuf + (size_t)g*N_*H_);
  unsigned lanoff = ((unsigned)ln) << 2;
  int hbase = h << 5;
  int dm = max(deg, __shfl_xor(deg, 32, 64));   // wave-uniform max degree

  float acc0 = 0.f, acc1 = 0.f;
  if (dm <= 32){
    int sv = 0; float sc = -1e30f;
    if (ln < deg){
      sv = csrc[start + ln];
      float e = esg[sv] + edv;
      sc = e > 0.f ? e : 0.2f*e;
    }
    float m = half_max(sc);
    float ex = (ln < deg) ? __expf(sc - m) : 0.f;
    float ssum = half_sum(ex);
    ex *= fastrcp(ssum + 1e-16f);
    unsigned pw = (f2bf_rtn(ex) << 16) | (unsigned)sv;   // alpha(bf16) | src_id
    for (int j0 = 0; j0 < dm; j0 += 8){
      unsigned wv[8]; float aa[8]; unsigned off[8];
      #pragma unroll
      for (int u = 0; u < 8; ++u){
        int j = j0 + u;
        wv[u] = (unsigned)__shfl((int)pw, hbase + j, 64);
        aa[u] = (j < deg) ? uasf(wv[u] & 0xffff0000u) : 0.f;
        off[u] = ((wv[u] & 0xffffu) << 7) + lanoff;
      }
      unsigned hv[8];
      #pragma unroll
      for (int u = 0; u < 8; ++u)
        hv[u] = *(const unsigned*)(hg + off[u]);
      #pragma unroll
      for (int u = 0; u < 8; ++u){
        acc0 = fmaf(aa[u], uasf(hv[u] << 16), acc0);
        acc1 = fmaf(aa[u], uasf(hv[u] & 0xffff0000u), acc1);
      }
    }
  } else {
    // general chunked path (deg > 32): 32-wide chunks per half
    float m = -1e30f;
    for (int base = 0; base < deg; base += 32){
      int i = base + ln;
      if (i < deg){
        int s = csrc[start + i];
        float e = esg[s] + edv;
        float t = e > 0.f ? e : 0.2f*e;
        m = fmaxf(m, t);
      }
    }
    m = half_max(m);
    float ssum = 0.f;
    for (int base = 0; base < deg; base += 32){
      int i = base + ln;
      if (i < deg){
        int s = csrc[start + i];
        float e = esg[s] + edv;
        float t = e > 0.f ? e : 0.2f*e;
        ssum += __expf(t - m);
      }
    }
    ssum = half_sum(ssum);
    float inv = fastrcp(ssum + 1e-16f);
    for (int base = 0; base < dm; base += 32){
      int i = base + ln;
      int sv = 0; float ex = 0.f;
      if (i < deg){
        sv = csrc[start + i];
        float e = esg[sv] + edv;
        float t = e > 0.f ? e : 0.2f*e;
        ex = __expf(t - m) * inv;
      }
      unsigned pw = (f2bf_rtn(ex) << 16) | (unsigned)sv;
      int rem = dm - base; if (rem > 32) rem = 32;
      int myrem = deg - base;
      for (int j0 = 0; j0 < rem; j0 += 8){
        unsigned wv[8]; float aa[8]; unsigned off[8];
        #pragma unroll
        for (int u = 0; u < 8; ++u){
          int j = j0 + u;
          wv[u] = (unsigned)__shfl((int)pw, hbase + j, 64);
          aa[u] = (j < myrem) ? uasf(wv[u] & 0xffff0000u) : 0.f;
          off[u] = ((wv[u] & 0xffffu) << 7) + lanoff;
        }
        unsigned hv[8];
        #pragma unroll
        for (int u = 0; u < 8; ++u)
          hv[u] = *(const unsigned*)(hg + off[u]);
        #pragma unroll
        for (int u = 0; u < 8; ++u){
          acc0 = fmaf(aa[u], uasf(hv[u] << 16), acc0);
          acc1 = fmaf(aa[u], uasf(hv[u] & 0xffff0000u), acc1);
        }
      }
    }
  }
  float2 bv = ((const float2*)bias)[ln];
  float2 o2;
  o2.x = gelu_exact(acc0 + bv.x);
  o2.y = gelu_exact(acc1 + bv.y);
  ((float2*)(gout + (size_t)gd*H_))[ln] = o2;
}

// ---------- LSTM via MFMA: Z = [H | X_t] @ [Whh^T ; Wih^T], K=128 fused ----------
__global__ __launch_bounds__(256) void lstm_mfma_kernel(
    const float* __restrict__ xin,   // flat [BN*T, 64]: row = seq*T + t
    const float* __restrict__ Wih,   // [256][64] row-major
    const float* __restrict__ Whh,   // [256][64] row-major
    const float* __restrict__ bih, const float* __restrict__ bhh,
    float* __restrict__ hfin){
  __shared__ __align__(16) unsigned short Hlds[16*LSTM_PAD];
  int tid = threadIdx.x;
  int lane = tid & 63, wave = tid >> 6;
  int q = lane >> 4, c = lane & 15;
  int s0 = blockIdx.x * 16;

  bf16x8 Bf[4][4];
  #pragma unroll
  for (int g = 0; g < 4; ++g){
    int n = g*64 + wave*16 + c;
    #pragma unroll
    for (int ks = 0; ks < 4; ++ks){
      const float* srcp = (ks < 2) ? (Whh + (size_t)n*64 + ks*32 + q*8)
                                   : (Wih + (size_t)n*64 + (ks-2)*32 + q*8);
      float4 a = ((const float4*)srcp)[0];
      float4 b = ((const float4*)srcp)[1];
      Bf[g][ks] = pack8(a, b);
    }
  }
  float bsum[4];
  #pragma unroll
  for (int g = 0; g < 4; ++g){
    int n = g*64 + wave*16 + c;
    bsum[g] = bih[n] + bhh[n];
  }
  for (int i = tid; i < 16*LSTM_PAD; i += 256) Hlds[i] = 0;
  float cst[4] = {0.f, 0.f, 0.f, 0.f};
  __syncthreads();

  for (int t = 0; t < T_; ++t){
    const float4* xr4 = (const float4*)(xin + ((size_t)(s0 + c)*T_ + t)*64);
    float4 x0 = xr4[q*2],     x1 = xr4[q*2 + 1];
    float4 x2 = xr4[8 + q*2], x3 = xr4[8 + q*2 + 1];
    bf16x8 Ax0 = pack8(x0, x1);
    bf16x8 Ax1 = pack8(x2, x3);
    const bf16x8* hrow = (const bf16x8*)(Hlds + c*LSTM_PAD);
    bf16x8 Ah0 = hrow[q];
    bf16x8 Ah1 = hrow[4 + q];

    f32x4 acc[4];
    #pragma unroll
    for (int g = 0; g < 4; ++g){ acc[g][0]=bsum[g]; acc[g][1]=bsum[g]; acc[g][2]=bsum[g]; acc[g][3]=bsum[g]; }
    #pragma unroll
    for (int g = 0; g < 4; ++g) acc[g] = __builtin_amdgcn_mfma_f32_16x16x32_bf16(Ah0, Bf[g][0], acc[g], 0, 0, 0);
    #pragma unroll
    for (int g = 0; g < 4; ++g) acc[g] = __builtin_amdgcn_mfma_f32_16x16x32_bf16(Ah1, Bf[g][1], acc[g], 0, 0, 0);
    #pragma unroll
    for (int g = 0; g < 4; ++g) acc[g] = __builtin_amdgcn_mfma_f32_16x16x32_bf16(Ax0, Bf[g][2], acc[g], 0, 0, 0);
    #pragma unroll
    for (int g = 0; g < 4; ++g) acc[g] = __builtin_amdgcn_mfma_f32_16x16x32_bf16(Ax1, Bf[g][3], acc[g], 0, 0, 0);

    float hv[4];
    #pragma unroll
    for (int r = 0; r < 4; ++r){
      float zi = acc[0][r], zf = acc[1][r], zg = acc[2][r], zo = acc[3][r];
      cst[r] = sigf(zf)*cst[r] + sigf(zi)*tanhfast(zg);
      hv[r] = sigf(zo)*tanhfast(cst[r]);
    }
    if (t == T_-1){
      #pragma unroll
      for (int r = 0; r < 4; ++r)
        hfin[(size_t)(s0 + q*4 + r)*64 + wave*16 + c] = hv[r];
    } else {
      __syncthreads();
      #pragma unroll
      for (int r = 0; r < 4; ++r)
        Hlds[(q*4 + r)*LSTM_PAD + wave*16 + c] = (unsigned short)f2bf_rtn(hv[r]);
      __syncthreads();
    }
  }
}

// ---------- LayerNorm (last step) + dense [64,12]; dual-dtype store ----------
__global__ __launch_bounds__(256) void final_kernel(
    const float* __restrict__ hfin, const float* __restrict__ lng, const float* __restrict__ lnb,
    const float* __restrict__ dW, const float* __restrict__ db,
    const int* __restrict__ flag, void* __restrict__ outv){
  __shared__ float sm[4][64];
  int lane = threadIdx.x & 63, wave = threadIdx.x >> 6;
  int s = blockIdx.x*4 + wave;
  float h = hfin[(size_t)s*64 + lane];
  float mu = wave_sum(h) * (1.f/64.f);
  float dev = h - mu;
  float var = wave_sum(dev*dev) * (1.f/64.f);
  float hn = dev * rsqrtf(var + 1e-5f) * lng[lane] + lnb[lane];
  sm[wave][lane] = hn;
  __syncthreads();
  if (lane < 12){
    float o = db[lane];
    #pragma unroll
    for (int k = 0; k < 64; ++k) o = fmaf(sm[wave][k], dW[k*12 + lane], o);
    if (*flag) ((unsigned short*)outv)[(size_t)s*12 + lane] = (unsigned short)f2bf_rtn(o);
    else       ((float*)outv)[(size_t)s*12 + lane] = o;
  }
}

extern "C" void kernel_launch(void* const* d_in, const int* in_sizes, int n_in,
                              void* d_out, int out_size, void* d_ws, size_t ws_size,
                              hipStream_t stream) {
  const int* esrc = (const int*)d_in[1];
  const int* edst = (const int*)d_in[2];

  static const int sizes[18] = {512, 64, 4096, 64, 64, 64, 4096, 64, 64, 64,
                                16384, 16384, 256, 256, 64, 64, 768, 12};
  static const int srcidx[18] = {3, 4, 5, 6, 7, 8, 9, 10, 11, 12,
                                 13, 14, 15, 16, 17, 18, 19, 20};
  ConvArgs ca;
  {
    int acc = 0;
    for (int i = 0; i < 18; ++i){ ca.src[i] = d_in[srcidx[i]]; ca.off[i] = acc; acc += sizes[i]; }
    ca.off[18] = acc;   // == NPARAM_
  }

  float* P     = (float*)d_ws;               // [NPARAM_PAD_]
  float* bufA  = P + NPARAM_PAD_;            // gout1 -> g2out
  float* bufB  = bufA + (size_t)GNH_;        // hbuf(bf16) -> hfin(f32)
  float* esb   = bufB + (size_t)GNH_;
  float* edb   = esb  + (size_t)G_*N_;
  int*   counts= (int*)(edb + (size_t)G_*N_);
  int*   cursor= counts + N_;
  int*   offs  = cursor + N_;
  int*   csrc  = offs + (N_ + 1);
  int*   flag  = csrc + E_;
  float* wcb   = (float*)(flag + 1);         // Wc[512] + bc[64]
  unsigned short* hbuf = (unsigned short*)bufB;
  float* hfin  = bufB;                       // alias (hbuf dead after agg#2)

  const float* pfcW = P + 0;
  const float* pfcb = P + 512;
  const float* pg1W = P + 576;
  const float* pg1b = P + 4672;
  const float* pg1as= P + 4736;
  const float* pg1ad= P + 4800;
  const float* pg2W = P + 4864;
  const float* pg2b = P + 8960;
  const float* pg2as= P + 9024;
  const float* pg2ad= P + 9088;
  const float* pWih = P + 9152;
  const float* pWhh = P + 25536;
  const float* pbih = P + 41920;
  const float* pbhh = P + 42176;
  const float* plng = P + 42432;
  const float* plnb = P + 42496;
  const float* pdW  = P + 42560;
  const float* pdb  = P + 43328;

  detect_kernel<<<1, 256, 0, stream>>>((const unsigned*)d_in[0], flag);
  convert_kernel<<<(NPARAM_ + 255)/256, 256, 0, stream>>>(ca, flag, P);
  wc_kernel<<<1, 512, 0, stream>>>(pfcW, pfcb, pg1W, wcb, wcb + 512);

  zero_kernel<<<16, 256, 0, stream>>>(counts, 2*N_);
  count_kernel<<<(E_+255)/256, 256, 0, stream>>>(edst, counts);
  scan_kernel<<<1, 64, 0, stream>>>(counts, offs);
  fill_kernel<<<(E_+255)/256, 256, 0, stream>>>(esrc, edst, offs, cursor, csrc);

  gat_h1_fused_kernel<<<750, 256, 0, stream>>>(d_in[0], flag, wcb, wcb + 512, pg1as, pg1ad, hbuf, esb, edb);
  gat_agg_kernel<<<12000, 256, 0, stream>>>(hbuf, esb, edb, offs, csrc, pg1b, bufA);

  gat_h2_mfma_kernel<<<750, 256, 0, stream>>>(bufA, pg2W, pg2as, pg2ad, hbuf, esb, edb);
  gat_agg_kernel<<<12000, 256, 0, stream>>>(hbuf, esb, edb, offs, csrc, pg2b, bufA);

  lstm_mfma_kernel<<<250, 256, 0, stream>>>(bufA, pWih, pWhh, pbih, pbhh, hfin);
  final_kernel<<<1000, 256, 0, stream>>>(hfin, plng, plnb, pdW, pdb, flag, d_out);
}